// Round 1
// baseline (5701.505 us; speedup 1.0000x reference)
//
#include <hip/hip_runtime.h>

// ---------------------------------------------------------------------------
// RecurrentEncoderDecoder: persistent-kernel LSTM seq2seq on MI355X (gfx950)
// B=64, H=512, T_enc=256, T_dec=96. 256 blocks x 256 thr (one per CU).
// R3: barrier-free DATAFLOW. All recurrent state lives in write-once slot
// arrays memset to 0xFF (bf16 0xFFFF / fp32 0xFFFFFFFF = NaN, impossible for
// LSTM h/c/ELU outputs). Consumers poll the data itself (sc0 sc1, IF$-level)
// until no sentinel remains -> producer store + consumer poll = ~2 IF$ round
// trips per step instead of the ~6-8 of the R2 flag-gather grid barrier.
// h is stored as word-atomic u32 pairs (2 bf16) so u32-granular sentinel
// checks can never observe a half-written word. One 1-hop flag barrier
// remains (pre-merge). y-feedback is folded into dec-L0 via an extra MFMA
// column against out_w row 0, removing the blk128->YFLAG->L0 serial hop.
// ---------------------------------------------------------------------------

#define BLOCKS 256

typedef short bf16x8 __attribute__((ext_vector_type(8)));
typedef float f32x4  __attribute__((ext_vector_type(4)));
typedef unsigned u32x4 __attribute__((ext_vector_type(4)));
typedef unsigned short u16;

__device__ __forceinline__ f32x4 MFMA16(bf16x8 a, bf16x8 b, f32x4 c) {
  return __builtin_amdgcn_mfma_f32_16x16x32_bf16(a, b, c, 0, 0, 0);
}

__device__ __forceinline__ u16 bfr(float f) {  // fp32 -> bf16 RNE
  unsigned u = __float_as_uint(f);
  u += 0x7FFFu + ((u >> 16) & 1u);
  return (u16)(u >> 16);
}
__device__ __forceinline__ bf16x8 pack8(float4 a, float4 b) {
  bf16x8 r;
  r[0] = (short)bfr(a.x); r[1] = (short)bfr(a.y); r[2] = (short)bfr(a.z); r[3] = (short)bfr(a.w);
  r[4] = (short)bfr(b.x); r[5] = (short)bfr(b.y); r[6] = (short)bfr(b.z); r[7] = (short)bfr(b.w);
  return r;
}
__device__ __forceinline__ bf16x8 loadW8(const float* p) {
  float4 a = *(const float4*)p;
  float4 b = *(const float4*)(p + 4);
  return pack8(a, b);
}
__device__ __forceinline__ float sigm(float x) { return 1.0f / (1.0f + __expf(-x)); }
__device__ __forceinline__ float tanh_f(float x) {
  float a = fabsf(x);
  float e = __expf(-2.0f * a);
  float t = (1.0f - e) / (1.0f + e);
  return x < 0.0f ? -t : t;
}
__device__ __forceinline__ float lstm_h(const float pre[4], float& c) {
  float ig = sigm(pre[0]);
  float fg = sigm(pre[1]);
  float gg = tanh_f(pre[2]);
  float og = sigm(pre[3]);
  c = fg * c + ig * gg;
  return og * tanh_f(c);
}
__device__ __forceinline__ float elu(float v) { return v > 0.f ? v : (__expf(v) - 1.0f); }

// ---- coherent (IF$-level, L1/L2-bypass) access helpers ----
__device__ __forceinline__ void st_u32_coh(unsigned* p, unsigned v) {
  asm volatile("global_store_dword %0, %1, off sc0 sc1" :: "v"(p), "v"(v) : "memory");
}
__device__ __forceinline__ void st_f32_coh(float* p, float v) {
  asm volatile("global_store_dword %0, %1, off sc0 sc1" :: "v"(p), "v"(v) : "memory");
}
__device__ __forceinline__ float ld_f32_coh(const float* p) {
  float r;
  asm volatile("global_load_dword %0, %1, off sc0 sc1\n\ts_waitcnt vmcnt(0)"
               : "=&v"(r) : "v"(p) : "memory");
  return r;
}
__device__ __forceinline__ u32x4 ld_u32x4_coh(const unsigned* p) {
  u32x4 r;
  asm volatile("global_load_dwordx4 %0, %1, off sc0 sc1\n\ts_waitcnt vmcnt(0)"
               : "=&v"(r) : "v"(p) : "memory");
  return r;
}
// Load one A-tile (16 bf16x8 frags, 64B stride) coherently; waits vmcnt(0).
__device__ __forceinline__ void ld_tile_coh(const u16* base, bf16x8 f[16]) {
  asm volatile(
    "global_load_dwordx4 %0, %16, off sc0 sc1\n\t"
    "global_load_dwordx4 %1, %16, off offset:64 sc0 sc1\n\t"
    "global_load_dwordx4 %2, %16, off offset:128 sc0 sc1\n\t"
    "global_load_dwordx4 %3, %16, off offset:192 sc0 sc1\n\t"
    "global_load_dwordx4 %4, %16, off offset:256 sc0 sc1\n\t"
    "global_load_dwordx4 %5, %16, off offset:320 sc0 sc1\n\t"
    "global_load_dwordx4 %6, %16, off offset:384 sc0 sc1\n\t"
    "global_load_dwordx4 %7, %16, off offset:448 sc0 sc1\n\t"
    "global_load_dwordx4 %8, %16, off offset:512 sc0 sc1\n\t"
    "global_load_dwordx4 %9, %16, off offset:576 sc0 sc1\n\t"
    "global_load_dwordx4 %10, %16, off offset:640 sc0 sc1\n\t"
    "global_load_dwordx4 %11, %16, off offset:704 sc0 sc1\n\t"
    "global_load_dwordx4 %12, %16, off offset:768 sc0 sc1\n\t"
    "global_load_dwordx4 %13, %16, off offset:832 sc0 sc1\n\t"
    "global_load_dwordx4 %14, %16, off offset:896 sc0 sc1\n\t"
    "global_load_dwordx4 %15, %16, off offset:960 sc0 sc1\n\t"
    "s_waitcnt vmcnt(0)"
    : "=&v"(f[0]), "=&v"(f[1]), "=&v"(f[2]), "=&v"(f[3]),
      "=&v"(f[4]), "=&v"(f[5]), "=&v"(f[6]), "=&v"(f[7]),
      "=&v"(f[8]), "=&v"(f[9]), "=&v"(f[10]), "=&v"(f[11]),
      "=&v"(f[12]), "=&v"(f[13]), "=&v"(f[14]), "=&v"(f[15])
    : "v"(base)
    : "memory");
}
// Same but WITHOUT the wait — caller must s_waitcnt vmcnt(0) + sched_barrier.
__device__ __forceinline__ void ld_tile_issue(const u16* base, bf16x8 f[16]) {
  asm volatile(
    "global_load_dwordx4 %0, %16, off sc0 sc1\n\t"
    "global_load_dwordx4 %1, %16, off offset:64 sc0 sc1\n\t"
    "global_load_dwordx4 %2, %16, off offset:128 sc0 sc1\n\t"
    "global_load_dwordx4 %3, %16, off offset:192 sc0 sc1\n\t"
    "global_load_dwordx4 %4, %16, off offset:256 sc0 sc1\n\t"
    "global_load_dwordx4 %5, %16, off offset:320 sc0 sc1\n\t"
    "global_load_dwordx4 %6, %16, off offset:384 sc0 sc1\n\t"
    "global_load_dwordx4 %7, %16, off offset:448 sc0 sc1\n\t"
    "global_load_dwordx4 %8, %16, off offset:512 sc0 sc1\n\t"
    "global_load_dwordx4 %9, %16, off offset:576 sc0 sc1\n\t"
    "global_load_dwordx4 %10, %16, off offset:640 sc0 sc1\n\t"
    "global_load_dwordx4 %11, %16, off offset:704 sc0 sc1\n\t"
    "global_load_dwordx4 %12, %16, off offset:768 sc0 sc1\n\t"
    "global_load_dwordx4 %13, %16, off offset:832 sc0 sc1\n\t"
    "global_load_dwordx4 %14, %16, off offset:896 sc0 sc1\n\t"
    "global_load_dwordx4 %15, %16, off offset:960 sc0 sc1"
    : "=&v"(f[0]), "=&v"(f[1]), "=&v"(f[2]), "=&v"(f[3]),
      "=&v"(f[4]), "=&v"(f[5]), "=&v"(f[6]), "=&v"(f[7]),
      "=&v"(f[8]), "=&v"(f[9]), "=&v"(f[10]), "=&v"(f[11]),
      "=&v"(f[12]), "=&v"(f[13]), "=&v"(f[14]), "=&v"(f[15])
    : "v"(base)
    : "memory");
}

// max over all 64 u32 words of a tile; == 0xFFFFFFFF iff any word unwritten.
__device__ __forceinline__ unsigned tile_max(const bf16x8 f[16]) {
  unsigned m = 0u;
  #pragma unroll
  for (int k = 0; k < 16; ++k) {
    u32x4 w = __builtin_bit_cast(u32x4, f[k]);
    unsigned a = w.x > w.y ? w.x : w.y;
    unsigned b = w.z > w.w ? w.z : w.w;
    unsigned cm = a > b ? a : b;
    m = m > cm ? m : cm;
  }
  return m;
}
__device__ __forceinline__ void poll_tile(const u16* base, bf16x8 f[16]) {
  ld_tile_coh(base, f);
  int miss = 0;
  while (__any(tile_max(f) == 0xFFFFFFFFu)) {
    if (++miss > 2) __builtin_amdgcn_s_sleep(2);
    ld_tile_coh(base, f);
  }
}
__device__ __forceinline__ void poll_tile2(const u16* b0, const u16* b1,
                                           bf16x8 f0[16], bf16x8 f1[16]) {
  ld_tile_issue(b0, f0);
  ld_tile_issue(b1, f1);
  asm volatile("s_waitcnt vmcnt(0)" ::: "memory");
  __builtin_amdgcn_sched_barrier(0);   // rule #18: fence reads of issue-asm outs
  int miss = 0;
  while (__any(tile_max(f0) == 0xFFFFFFFFu)) {
    if (++miss > 2) __builtin_amdgcn_s_sleep(2);
    ld_tile_coh(b0, f0);
  }
  miss = 0;
  while (__any(tile_max(f1) == 0xFFFFFFFFu)) {
    if (++miss > 2) __builtin_amdgcn_s_sleep(2);
    ld_tile_coh(b1, f1);
  }
}
__device__ __forceinline__ float poll_f32(const float* p) {
  float v = ld_f32_coh(p);
  int miss = 0;
  while (__float_as_uint(v) == 0xFFFFFFFFu) {
    if (++miss > 2) __builtin_amdgcn_s_sleep(2);
    v = ld_f32_coh(p);
  }
  return v;
}

// ---- workspace layout (byte offsets) ----
static constexpr size_t SZ_SLOT  = (size_t)64 * 512 * 2;          // [64][512] bf16
static constexpr size_t OFF_OF   = 65536;                         // enc L0 fw: 257 slots
static constexpr size_t OFF_OBR  = OFF_OF  + 257 * SZ_SLOT;       // enc L0 bw (reversed)
static constexpr size_t OFF_H1F  = OFF_OBR + 257 * SZ_SLOT;       // enc L1 fw h: 257 slots
static constexpr size_t OFF_H1B  = OFF_H1F + 257 * SZ_SLOT;       // enc L1 bw h: 257 slots
static constexpr size_t OFF_DH0  = OFF_H1B + 257 * SZ_SLOT;       // dec L0 h: 97 slots
static constexpr size_t OFF_DH1  = OFF_DH0 + 97 * SZ_SLOT;        // dec L1 h: 97 slots
static constexpr size_t OFF_SBUF = OFF_DH1 + 97 * SZ_SLOT;        // fp32 [128][2048]
static constexpr size_t OFF_CDEC = OFF_SBUF + (size_t)128 * 2048 * 4;
static constexpr size_t WS_NEED  = OFF_CDEC + (size_t)2 * 64 * 512 * 4;  // ~78 MiB

// Single remaining barrier (pre-merge): 1-hop all-see-all flags.
__device__ __forceinline__ void gridbar1(char* ws) {
  asm volatile("s_waitcnt vmcnt(0)" ::: "memory");  // drain own SB stores to IF$
  __syncthreads();
  unsigned* flags = (unsigned*)ws;
  if (threadIdx.x == 0) st_u32_coh(flags + blockIdx.x, 1u);
  if (threadIdx.x < 64) {
    int miss = 0;
    for (;;) {
      u32x4 f4 = ld_u32x4_coh(flags + (size_t)threadIdx.x * 4);
      unsigned a = f4.x < f4.y ? f4.x : f4.y;
      unsigned b = f4.z < f4.w ? f4.z : f4.w;
      unsigned mn = a < b ? a : b;
      if (!__any(mn == 0u)) break;
      if (++miss > 4) __builtin_amdgcn_s_sleep(2);
    }
  }
  __syncthreads();
}

__global__ __launch_bounds__(256, 1) void red_lstm(
    const float* __restrict__ X,   const float* __restrict__ FUT,
    const float* __restrict__ eWih0,  const float* __restrict__ eWhh0,  const float* __restrict__ eB0,
    const float* __restrict__ eWih0r, const float* __restrict__ eWhh0r, const float* __restrict__ eB0r,
    const float* __restrict__ eWih1,  const float* __restrict__ eWhh1,  const float* __restrict__ eB1,
    const float* __restrict__ eWih1r, const float* __restrict__ eWhh1r, const float* __restrict__ eB1r,
    const float* __restrict__ dWih0,  const float* __restrict__ dWhh0,  const float* __restrict__ dB0,
    const float* __restrict__ dWih1,  const float* __restrict__ dWhh1,  const float* __restrict__ dB1,
    const float* __restrict__ bW,  const float* __restrict__ bB,
    const float* __restrict__ oW,  const float* __restrict__ oB,
    float* __restrict__ OUT, char* __restrict__ ws)
{
  const int blk  = blockIdx.x;
  const int tid  = threadIdx.x;
  const int lane = tid & 63;
  const int wave = tid >> 6;
  const int n16  = lane & 15;
  const int quad = lane >> 4;
  const int rowg = wave * 16 + n16;  // batch row for A-frag loads
  const int jl   = tid & 3;          // update-thread: hidden-within-block
  const int bb   = tid >> 2;         // update-thread: batch row

  u16*   OF  = (u16*)(ws + OFF_OF);
  u16*   OBR = (u16*)(ws + OFF_OBR);
  u16*   H1F = (u16*)(ws + OFF_H1F);
  u16*   H1B = (u16*)(ws + OFF_H1B);
  u16*   DH0 = (u16*)(ws + OFF_DH0);
  u16*   DH1 = (u16*)(ws + OFF_DH1);
  float* SB  = (float*)(ws + OFF_SBUF);
  float* CD  = (float*)(ws + OFF_CDEC);

  __shared__ float g_s[64 * 20];

  // =======================================================================
  // ENCODER LAYER 0  (blocks 0..127 = fw, 128..255 = bw; 4 hidden/block)
  // Pure dataflow: poll slot s until no 0xFFFF sentinel, no barriers.
  // =======================================================================
  {
    const bool fw = (blk < 128);
    const int  hb = fw ? blk : (blk - 128);
    const int  j0 = hb * 4;
    const int  col = j0 + (n16 & 3) + 512 * (n16 >> 2);
    const float* whh = fw ? eWhh0 : eWhh0r;
    const float* wih = fw ? eWih0 : eWih0r;
    const float* bia = fw ? eB0 : eB0r;
    u16* buf = fw ? OF : OBR;   // slot[t]=input state, slot[t+1]=output of step t

    bf16x8 B[16];
    {
      const float* wr = whh + (size_t)col * 512 + quad * 8;
      #pragma unroll
      for (int kk = 0; kk < 16; ++kk) B[kk] = loadW8(wr + kk * 32);
    }
    float wr9[4][9], b4[4];
    #pragma unroll
    for (int g = 0; g < 4; ++g) {
      int cg = j0 + jl + 512 * g;
      b4[g] = bia[cg];
      #pragma unroll
      for (int k = 0; k < 9; ++k) wr9[g][k] = wih[cg * 9 + k];
    }
    float c = 0.0f;

    #pragma unroll 1
    for (int s = 0; s < 256; ++s) {
      bf16x8 T[16];
      poll_tile(buf + ((size_t)s * 64 + rowg) * 512 + quad * 8, T);
      f32x4 a0 = {0.f,0.f,0.f,0.f}, a1 = {0.f,0.f,0.f,0.f};
      #pragma unroll
      for (int kk = 0; kk < 16; kk += 2) {
        a0 = MFMA16(T[kk],     B[kk],     a0);
        a1 = MFMA16(T[kk + 1], B[kk + 1], a1);
      }
      f32x4 acc = a0 + a1;
      #pragma unroll
      for (int r = 0; r < 4; ++r)
        g_s[(wave * 16 + quad * 4 + r) * 20 + n16] = acc[r];
      __syncthreads();

      const int t = fw ? s : (255 - s);
      float pre[4];
      #pragma unroll
      for (int g = 0; g < 4; ++g) pre[g] = g_s[bb * 20 + jl + 4 * g] + b4[g];
      const float* xp = X + ((size_t)bb * 256 + t) * 9;
      #pragma unroll
      for (int k = 0; k < 9; ++k) {
        float xv = xp[k];
        #pragma unroll
        for (int g = 0; g < 4; ++g) pre[g] += xv * wr9[g][k];
      }
      float h = lstm_h(pre, c);
      float hn = __shfl_down(h, 1);      // pair for word-atomic u32 store
      if ((jl & 1) == 0) {
        unsigned pk = (unsigned)bfr(h) | ((unsigned)bfr(hn) << 16);
        st_u32_coh((unsigned*)(buf + ((size_t)(s + 1) * 64 + bb) * 512 + j0 + jl), pk);
      }
      if (s == 255) {
        int co = fw ? 0 : 512;
        st_f32_coh(SB + (size_t)bb * 2048 + co + j0 + jl, h);
        st_f32_coh(SB + (size_t)(64 + bb) * 2048 + co + j0 + jl, c);
      }
      __syncthreads();                   // protect g_s reuse next iteration
    }
  }

  // =======================================================================
  // ENCODER LAYER 1  K = 512 (own h, polled) + 512 (of_t) + 512 (ob_t)
  // of/ob are static once any L1 step >=1 is reachable -> cached loads.
  // =======================================================================
  {
    const bool fw = (blk < 128);
    const int  hb = fw ? blk : (blk - 128);
    const int  j0 = hb * 4;
    const int  col = j0 + (n16 & 3) + 512 * (n16 >> 2);
    const float* whh = fw ? eWhh1 : eWhh1r;
    const float* wih = fw ? eWih1 : eWih1r;
    const float* bia = fw ? eB1 : eB1r;
    u16* hsl = fw ? H1F : H1B;           // 257 write-once slots

    bf16x8 B[48];
    {
      const float* wr = whh + (size_t)col * 512 + quad * 8;
      #pragma unroll
      for (int kk = 0; kk < 16; ++kk) B[kk] = loadW8(wr + kk * 32);
      const float* wr2 = wih + (size_t)col * 1024 + quad * 8;
      #pragma unroll
      for (int kk = 0; kk < 32; ++kk) B[16 + kk] = loadW8(wr2 + kk * 32);
    }
    float b4[4];
    #pragma unroll
    for (int g = 0; g < 4; ++g) b4[g] = bia[j0 + jl + 512 * g];
    float c = 0.0f;

    #pragma unroll 1
    for (int s = 0; s < 256; ++s) {
      const int slot_of = fw ? (s + 1)   : (256 - s);
      const int slot_ob = fw ? (256 - s) : (s + 1);
      const u16* pof = OF  + ((size_t)slot_of * 64 + rowg) * 512 + quad * 8;
      const u16* pob = OBR + ((size_t)slot_ob * 64 + rowg) * 512 + quad * 8;
      f32x4 a0 = {0.f,0.f,0.f,0.f}, a1 = {0.f,0.f,0.f,0.f};
      if (s == 0) {                      // first step: coherent polls (gates on
        bf16x8 T[16];                    // the opposite L0 chain finishing)
        poll_tile(pof, T);
        #pragma unroll
        for (int kk = 0; kk < 16; kk += 2) {
          a0 = MFMA16(T[kk],     B[16 + kk],     a0);
          a1 = MFMA16(T[kk + 1], B[16 + kk + 1], a1);
        }
        poll_tile(pob, T);
        #pragma unroll
        for (int kk = 0; kk < 16; kk += 2) {
          a0 = MFMA16(T[kk],     B[32 + kk],     a0);
          a1 = MFMA16(T[kk + 1], B[32 + kk + 1], a1);
        }
      } else {                           // static by induction: cached loads
        bf16x8 T[16];
        #pragma unroll
        for (int kk = 0; kk < 16; ++kk) T[kk] = *(const bf16x8*)(pof + kk * 32);
        #pragma unroll
        for (int kk = 0; kk < 16; kk += 2) {
          a0 = MFMA16(T[kk],     B[16 + kk],     a0);
          a1 = MFMA16(T[kk + 1], B[16 + kk + 1], a1);
        }
        #pragma unroll
        for (int kk = 0; kk < 16; ++kk) T[kk] = *(const bf16x8*)(pob + kk * 32);
        #pragma unroll
        for (int kk = 0; kk < 16; kk += 2) {
          a0 = MFMA16(T[kk],     B[32 + kk],     a0);
          a1 = MFMA16(T[kk + 1], B[32 + kk + 1], a1);
        }
      }
      {
        bf16x8 T[16];
        poll_tile(hsl + ((size_t)s * 64 + rowg) * 512 + quad * 8, T);
        #pragma unroll
        for (int kk = 0; kk < 16; kk += 2) {
          a0 = MFMA16(T[kk],     B[kk],     a0);
          a1 = MFMA16(T[kk + 1], B[kk + 1], a1);
        }
      }
      f32x4 acc = a0 + a1;
      #pragma unroll
      for (int r = 0; r < 4; ++r)
        g_s[(wave * 16 + quad * 4 + r) * 20 + n16] = acc[r];
      __syncthreads();

      float pre[4];
      #pragma unroll
      for (int g = 0; g < 4; ++g) pre[g] = g_s[bb * 20 + jl + 4 * g] + b4[g];
      float h = lstm_h(pre, c);
      float hn = __shfl_down(h, 1);
      if ((jl & 1) == 0) {
        unsigned pk = (unsigned)bfr(h) | ((unsigned)bfr(hn) << 16);
        st_u32_coh((unsigned*)(hsl + ((size_t)(s + 1) * 64 + bb) * 512 + j0 + jl), pk);
      }
      if (s == 255) {
        int co = fw ? 1024 : 1536;
        st_f32_coh(SB + (size_t)bb * 2048 + co + j0 + jl, h);
        st_f32_coh(SB + (size_t)(64 + bb) * 2048 + co + j0 + jl, c);
      }
      __syncthreads();
    }
  }

  // single remaining barrier: SB complete -> merge may read it CACHED
  gridbar1(ws);

  // =======================================================================
  // MERGE: [h;c](128x2048) @ bidi_w^T + b, ELU  (fp32 VALU, blocks 0..127)
  // Each thread owns a col-PAIR so DH stores are word-atomic u32.
  // =======================================================================
  if (blk < 128 && tid < 128) {
    const int cp = tid & 3;
    const int rg = tid >> 2;             // 0..31
    const int c0 = blk * 8 + cp * 2;
    const float* w0 = bW + (size_t)c0 * 2048;
    const float* w1 = w0 + 2048;
    float am0[4], am1[4];
    #pragma unroll
    for (int r = 0; r < 4; ++r) { am0[r] = bB[c0]; am1[r] = bB[c0 + 1]; }
    #pragma unroll 1
    for (int k = 0; k < 2048; k += 4) {
      float4 wa = *(const float4*)(w0 + k);
      float4 wb = *(const float4*)(w1 + k);
      #pragma unroll
      for (int r = 0; r < 4; ++r) {
        float4 a = *(const float4*)(SB + (size_t)(rg * 4 + r) * 2048 + k);
        am0[r] += a.x * wa.x + a.y * wa.y + a.z * wa.z + a.w * wa.w;
        am1[r] += a.x * wb.x + a.y * wb.y + a.z * wb.z + a.w * wb.w;
      }
    }
    const int l = c0 >> 9, j = c0 & 511;
    #pragma unroll
    for (int r = 0; r < 4; ++r) {
      int row = rg * 4 + r;
      float v0 = elu(am0[r]);
      float v1 = elu(am1[r]);
      if (row < 64) {
        u16* dst = l ? DH1 : DH0;        // slot 0
        unsigned pk = (unsigned)bfr(v0) | ((unsigned)bfr(v1) << 16);
        st_u32_coh((unsigned*)(dst + (size_t)row * 512 + j), pk);
      } else {
        st_f32_coh(CD + ((size_t)l * 64 + (row - 64)) * 512 + j, v0);
        st_f32_coh(CD + ((size_t)l * 64 + (row - 64)) * 512 + j + 1, v1);
      }
    }
  }

  // =======================================================================
  // DECODER: dataflow chains. blocks 0..127 = L0 (y-feedback via extra MFMA
  // column vs out_w row 0); blocks 128..255 = L1; blk128 also full 9-col OUT.
  // =======================================================================
  if (blk < 128) {
    // ---------------- dec L0 ----------------
    const int j0 = blk * 4;
    const int col = j0 + (n16 & 3) + 512 * (n16 >> 2);
    bf16x8 BD[16], OW0[16];
    {
      const float* wr = dWhh0 + (size_t)col * 512 + quad * 8;
      #pragma unroll
      for (int kk = 0; kk < 16; ++kk) BD[kk] = loadW8(wr + kk * 32);
    }
    #pragma unroll
    for (int kk = 0; kk < 16; ++kk) {
      if (n16 == 0) OW0[kk] = loadW8(oW + quad * 8 + kk * 32);
      else { bf16x8 z = {0,0,0,0,0,0,0,0}; OW0[kk] = z; }
    }
    float wr9[4][9], b4[4];
    #pragma unroll
    for (int g = 0; g < 4; ++g) {
      int cg = j0 + jl + 512 * g;
      b4[g] = dB0[cg];
      #pragma unroll
      for (int k = 0; k < 9; ++k) wr9[g][k] = dWih0[cg * 9 + k];
    }
    const float ob0 = oB[0];
    float c = poll_f32(CD + (size_t)bb * 512 + j0 + jl);
    const float xlast = X[((size_t)bb * 256 + 255) * 9];

    #pragma unroll 1
    for (int t = 0; t < 96; ++t) {
      bf16x8 T0[16], T1[16];
      const u16* p0 = DH0 + ((size_t)t * 64 + rowg) * 512 + quad * 8;
      if (t == 0) {
        poll_tile(p0, T0);
      } else {
        poll_tile2(p0, DH1 + ((size_t)t * 64 + rowg) * 512 + quad * 8, T0, T1);
      }
      f32x4 a0 = {0.f,0.f,0.f,0.f}, a1 = {0.f,0.f,0.f,0.f};
      #pragma unroll
      for (int kk = 0; kk < 16; kk += 2) {
        a0 = MFMA16(T0[kk],     BD[kk],     a0);
        a1 = MFMA16(T0[kk + 1], BD[kk + 1], a1);
      }
      f32x4 acc = a0 + a1;
      #pragma unroll
      for (int r = 0; r < 4; ++r)
        g_s[(wave * 16 + quad * 4 + r) * 20 + n16] = acc[r];
      if (t >= 1) {
        f32x4 y0 = {0.f,0.f,0.f,0.f}, y1 = {0.f,0.f,0.f,0.f};
        #pragma unroll
        for (int kk = 0; kk < 16; kk += 2) {
          y0 = MFMA16(T1[kk],     OW0[kk],     y0);
          y1 = MFMA16(T1[kk + 1], OW0[kk + 1], y1);
        }
        f32x4 accy = y0 + y1;
        if (n16 == 0) {
          #pragma unroll
          for (int r = 0; r < 4; ++r)
            g_s[(wave * 16 + quad * 4 + r) * 20 + 16] = accy[r] + ob0;
        }
      }
      __syncthreads();

      float pre[4];
      #pragma unroll
      for (int g = 0; g < 4; ++g) pre[g] = g_s[bb * 20 + jl + 4 * g] + b4[g];
      float yp = (t == 0) ? xlast : g_s[bb * 20 + 16];
      #pragma unroll
      for (int g = 0; g < 4; ++g) pre[g] += yp * wr9[g][0];
      const float* fp = FUT + ((size_t)bb * 96 + t) * 8;
      #pragma unroll
      for (int k = 0; k < 8; ++k) {
        float fv = fp[k];
        #pragma unroll
        for (int g = 0; g < 4; ++g) pre[g] += fv * wr9[g][k + 1];
      }
      float h = lstm_h(pre, c);
      float hn = __shfl_down(h, 1);
      if ((jl & 1) == 0) {
        unsigned pk = (unsigned)bfr(h) | ((unsigned)bfr(hn) << 16);
        st_u32_coh((unsigned*)(DH0 + ((size_t)(t + 1) * 64 + bb) * 512 + j0 + jl), pk);
      }
      __syncthreads();
    }
  } else {
    // ---------------- dec L1 (+ blk128 out-projection) ----------------
    const int hb = blk - 128;
    const int j0 = hb * 4;
    const int col = j0 + (n16 & 3) + 512 * (n16 >> 2);
    bf16x8 BD[32];
    {
      const float* wr = dWhh1 + (size_t)col * 512 + quad * 8;
      #pragma unroll
      for (int kk = 0; kk < 16; ++kk) BD[kk] = loadW8(wr + kk * 32);
      const float* wr2 = dWih1 + (size_t)col * 512 + quad * 8;
      #pragma unroll
      for (int kk = 0; kk < 16; ++kk) BD[16 + kk] = loadW8(wr2 + kk * 32);
    }
    float b4[4];
    #pragma unroll
    for (int g = 0; g < 4; ++g) b4[g] = dB1[j0 + jl + 512 * g];
    bf16x8 OBW[16];
    float obv = 0.0f;
    if (blk == 128) {
      if (n16 < 9) {
        const float* wr = oW + (size_t)n16 * 512 + quad * 8;
        #pragma unroll
        for (int kk = 0; kk < 16; ++kk) OBW[kk] = loadW8(wr + kk * 32);
        obv = oB[n16];
      } else {
        #pragma unroll
        for (int kk = 0; kk < 16; ++kk) { bf16x8 z = {0,0,0,0,0,0,0,0}; OBW[kk] = z; }
      }
    }
    float c = poll_f32(CD + ((size_t)64 + bb) * 512 + j0 + jl);

    #pragma unroll 1
    for (int t = 0; t < 96; ++t) {
      bf16x8 Th1[16], T0[16];
      poll_tile2(DH1 + ((size_t)t * 64 + rowg) * 512 + quad * 8,
                 DH0 + ((size_t)(t + 1) * 64 + rowg) * 512 + quad * 8, Th1, T0);
      f32x4 a0 = {0.f,0.f,0.f,0.f}, a1 = {0.f,0.f,0.f,0.f};
      #pragma unroll
      for (int kk = 0; kk < 16; kk += 2) {
        a0 = MFMA16(Th1[kk],     BD[kk],     a0);
        a1 = MFMA16(Th1[kk + 1], BD[kk + 1], a1);
      }
      #pragma unroll
      for (int kk = 0; kk < 16; kk += 2) {
        a0 = MFMA16(T0[kk],     BD[16 + kk],     a0);
        a1 = MFMA16(T0[kk + 1], BD[16 + kk + 1], a1);
      }
      f32x4 acc = a0 + a1;
      #pragma unroll
      for (int r = 0; r < 4; ++r)
        g_s[(wave * 16 + quad * 4 + r) * 20 + n16] = acc[r];
      __syncthreads();

      float pre[4];
      #pragma unroll
      for (int g = 0; g < 4; ++g) pre[g] = g_s[bb * 20 + jl + 4 * g] + b4[g];
      float h = lstm_h(pre, c);
      float hn = __shfl_down(h, 1);
      if ((jl & 1) == 0) {
        unsigned pk = (unsigned)bfr(h) | ((unsigned)bfr(hn) << 16);
        st_u32_coh((unsigned*)(DH1 + ((size_t)(t + 1) * 64 + bb) * 512 + j0 + jl), pk);
      }
      // blk128: y_{t-1} for OUT, from the DH1[t] tile already in registers.
      // Done AFTER the h-store so peers/L0 are never delayed by it.
      if (blk == 128 && t >= 1) {
        f32x4 y0 = {0.f,0.f,0.f,0.f}, y1 = {0.f,0.f,0.f,0.f};
        #pragma unroll
        for (int kk = 0; kk < 16; kk += 2) {
          y0 = MFMA16(Th1[kk],     OBW[kk],     y0);
          y1 = MFMA16(Th1[kk + 1], OBW[kk + 1], y1);
        }
        f32x4 accy = y0 + y1;
        #pragma unroll
        for (int r = 0; r < 4; ++r) {
          int b = wave * 16 + quad * 4 + r;
          float v = accy[r] + obv;
          if (n16 < 9) OUT[(size_t)b * 864 + (size_t)(t - 1) * 9 + n16] = v;
        }
      }
      __syncthreads();
    }
    if (blk == 128) {  // final output row t=95 (h1_95 = DH1 slot 96)
      bf16x8 T[16];
      poll_tile(DH1 + ((size_t)96 * 64 + rowg) * 512 + quad * 8, T);
      f32x4 y0 = {0.f,0.f,0.f,0.f}, y1 = {0.f,0.f,0.f,0.f};
      #pragma unroll
      for (int kk = 0; kk < 16; kk += 2) {
        y0 = MFMA16(T[kk],     OBW[kk],     y0);
        y1 = MFMA16(T[kk + 1], OBW[kk + 1], y1);
      }
      f32x4 accy = y0 + y1;
      #pragma unroll
      for (int r = 0; r < 4; ++r) {
        int b = wave * 16 + quad * 4 + r;
        float v = accy[r] + obv;
        if (n16 < 9) OUT[(size_t)b * 864 + (size_t)95 * 9 + n16] = v;
      }
    }
  }
}

extern "C" void kernel_launch(void* const* d_in, const int* in_sizes, int n_in,
                              void* d_out, int out_size, void* d_ws, size_t ws_size,
                              hipStream_t stream) {
  (void)in_sizes; (void)n_in; (void)out_size;
  if (ws_size < WS_NEED) return;

  const float* X      = (const float*)d_in[0];
  const float* FUT    = (const float*)d_in[1];
  const float* eWih0  = (const float*)d_in[3];
  const float* eWhh0  = (const float*)d_in[4];
  const float* eB0    = (const float*)d_in[5];
  const float* eWih0r = (const float*)d_in[6];
  const float* eWhh0r = (const float*)d_in[7];
  const float* eB0r   = (const float*)d_in[8];
  const float* eWih1  = (const float*)d_in[9];
  const float* eWhh1  = (const float*)d_in[10];
  const float* eB1    = (const float*)d_in[11];
  const float* eWih1r = (const float*)d_in[12];
  const float* eWhh1r = (const float*)d_in[13];
  const float* eB1r   = (const float*)d_in[14];
  const float* dWih0  = (const float*)d_in[15];
  const float* dWhh0  = (const float*)d_in[16];
  const float* dB0    = (const float*)d_in[17];
  const float* dWih1  = (const float*)d_in[18];
  const float* dWhh1  = (const float*)d_in[19];
  const float* dB1    = (const float*)d_in[20];
  const float* bW     = (const float*)d_in[21];
  const float* bB     = (const float*)d_in[22];
  const float* oW     = (const float*)d_in[23];
  const float* oB     = (const float*)d_in[24];

  char* ws = (char*)d_ws;
  // barrier flags
  hipMemsetAsync(ws, 0, 4096, stream);
  // dataflow sentinels: 0xFF = bf16 NaN / fp32 -NaN, impossible LSTM outputs.
  // slot 0 of each encoder array = initial h state = 0.
  hipMemsetAsync(ws + OFF_OF,            0x00, SZ_SLOT, stream);
  hipMemsetAsync(ws + OFF_OF + SZ_SLOT,  0xFF, 256 * SZ_SLOT, stream);
  hipMemsetAsync(ws + OFF_OBR,           0x00, SZ_SLOT, stream);
  hipMemsetAsync(ws + OFF_OBR + SZ_SLOT, 0xFF, 256 * SZ_SLOT, stream);
  hipMemsetAsync(ws + OFF_H1F,           0x00, SZ_SLOT, stream);
  hipMemsetAsync(ws + OFF_H1F + SZ_SLOT, 0xFF, 256 * SZ_SLOT, stream);
  hipMemsetAsync(ws + OFF_H1B,           0x00, SZ_SLOT, stream);
  hipMemsetAsync(ws + OFF_H1B + SZ_SLOT, 0xFF, 256 * SZ_SLOT, stream);
  hipMemsetAsync(ws + OFF_DH0,           0xFF, 97 * SZ_SLOT, stream);
  hipMemsetAsync(ws + OFF_DH1,           0xFF, 97 * SZ_SLOT, stream);
  hipMemsetAsync(ws + OFF_CDEC,          0xFF, (size_t)2 * 64 * 512 * 4, stream);

  red_lstm<<<BLOCKS, 256, 0, stream>>>(
      X, FUT,
      eWih0, eWhh0, eB0, eWih0r, eWhh0r, eB0r,
      eWih1, eWhh1, eB1, eWih1r, eWhh1r, eB1r,
      dWih0, dWhh0, dB0, dWih1, dWhh1, dB1,
      bW, bB, oW, oB,
      (float*)d_out, ws);
}

// Round 3
// 5638.680 us; speedup vs baseline: 1.0111x; 1.0111x over previous
//
#include <hip/hip_runtime.h>

// ---------------------------------------------------------------------------
// RecurrentEncoderDecoder: persistent-kernel LSTM seq2seq on MI355X (gfx950)
// B=64, H=512, T_enc=256, T_dec=96. 256 blocks x 256 thr (one per CU).
// R4 (resubmit; round 2 was an infra acquisition timeout, no measurement):
// epoch-flag dataflow + cached data loads.
//  - Signaling: per-block monotonic counters flags[256] (sc0 sc1). Producer:
//    data stores (sc0 sc1) -> vmcnt(0) -> flag store. Consumer: wave 0 polls
//    all 256 flags with ONE dwordx4/lane load; per-group thresholds.
//  - Data: ALL loads are plain cached. Safe: L2s are invalidated at dispatch
//    acquire; all cross-block data is written sc0 sc1 (write-through to IF$,
//    never allocated in any L2); slots are write-once and reads are
//    flag-gated after the write -> first cached read misses to IF$ = fresh,
//    and 16 blocks/XCD share the L2 line instead of 256 IF$ round trips.
//  - enc L1: of/ob tiles (static after encL0) issue BEFORE the flag wait so
//    only the own-h tile load is on the critical path.
//  - decoder: R3's rank-1 y-feedback (L0 computes y from DH1 via out_w row 0).
// ---------------------------------------------------------------------------

#define BLOCKS 256

typedef short bf16x8 __attribute__((ext_vector_type(8)));
typedef float f32x4  __attribute__((ext_vector_type(4)));
typedef unsigned u32x4 __attribute__((ext_vector_type(4)));
typedef unsigned short u16;

__device__ __forceinline__ f32x4 MFMA16(bf16x8 a, bf16x8 b, f32x4 c) {
  return __builtin_amdgcn_mfma_f32_16x16x32_bf16(a, b, c, 0, 0, 0);
}

__device__ __forceinline__ u16 bfr(float f) {  // fp32 -> bf16 RNE
  unsigned u = __float_as_uint(f);
  u += 0x7FFFu + ((u >> 16) & 1u);
  return (u16)(u >> 16);
}
__device__ __forceinline__ bf16x8 pack8(float4 a, float4 b) {
  bf16x8 r;
  r[0] = (short)bfr(a.x); r[1] = (short)bfr(a.y); r[2] = (short)bfr(a.z); r[3] = (short)bfr(a.w);
  r[4] = (short)bfr(b.x); r[5] = (short)bfr(b.y); r[6] = (short)bfr(b.z); r[7] = (short)bfr(b.w);
  return r;
}
__device__ __forceinline__ bf16x8 loadW8(const float* p) {
  float4 a = *(const float4*)p;
  float4 b = *(const float4*)(p + 4);
  return pack8(a, b);
}
__device__ __forceinline__ float sigm(float x) { return 1.0f / (1.0f + __expf(-x)); }
__device__ __forceinline__ float tanh_f(float x) {
  float a = fabsf(x);
  float e = __expf(-2.0f * a);
  float t = (1.0f - e) / (1.0f + e);
  return x < 0.0f ? -t : t;
}
__device__ __forceinline__ float lstm_h(const float pre[4], float& c) {
  float ig = sigm(pre[0]);
  float fg = sigm(pre[1]);
  float gg = tanh_f(pre[2]);
  float og = sigm(pre[3]);
  c = fg * c + ig * gg;
  return og * tanh_f(c);
}
__device__ __forceinline__ float elu(float v) { return v > 0.f ? v : (__expf(v) - 1.0f); }

// ---- coherent (IF$-level) helpers: flags + cross-block data STORES ----
__device__ __forceinline__ void st_u32_coh(unsigned* p, unsigned v) {
  asm volatile("global_store_dword %0, %1, off sc0 sc1" :: "v"(p), "v"(v) : "memory");
}
__device__ __forceinline__ void st_f32_coh(float* p, float v) {
  asm volatile("global_store_dword %0, %1, off sc0 sc1" :: "v"(p), "v"(v) : "memory");
}
__device__ __forceinline__ u32x4 ld_u32x4_coh(const unsigned* p) {
  u32x4 r;
  asm volatile("global_load_dwordx4 %0, %1, off sc0 sc1\n\ts_waitcnt vmcnt(0)"
               : "=&v"(r) : "v"(p) : "memory");
  return r;
}

// ---- workspace layout (byte offsets) ----
static constexpr size_t SZ_SLOT  = (size_t)64 * 512 * 2;          // [64][512] bf16
static constexpr size_t OFF_OF   = 65536;                         // enc L0 fw: 257 slots
static constexpr size_t OFF_OBR  = OFF_OF  + 257 * SZ_SLOT;       // enc L0 bw (reversed)
static constexpr size_t OFF_H1F  = OFF_OBR + 257 * SZ_SLOT;       // enc L1 fw h: 257 slots
static constexpr size_t OFF_H1B  = OFF_H1F + 257 * SZ_SLOT;       // enc L1 bw h: 257 slots
static constexpr size_t OFF_DH0  = OFF_H1B + 257 * SZ_SLOT;       // dec L0 h: 97 slots
static constexpr size_t OFF_DH1  = OFF_DH0 + 97 * SZ_SLOT;        // dec L1 h: 97 slots
static constexpr size_t OFF_SBUF = OFF_DH1 + 97 * SZ_SLOT;        // fp32 [128][2048]
static constexpr size_t OFF_CDEC = OFF_SBUF + (size_t)128 * 2048 * 4;
static constexpr size_t WS_NEED  = OFF_CDEC + (size_t)2 * 64 * 512 * 4;

// Wait until min(flags[0..127]) >= thrL and min(flags[128..255]) >= thrH.
// Wave 0 polls (lane L covers flags[4L..4L+3]); other waves park at barrier.
__device__ __forceinline__ void wait_flags(char* ws, unsigned thrL, unsigned thrH) {
  const unsigned* flags = (const unsigned*)ws;
  const int t = threadIdx.x;
  if (t < 64 && (thrL | thrH)) {
    unsigned thr = (t < 32) ? thrL : thrH;
    const unsigned* p = flags + (size_t)t * 4;
    int miss = 0;
    for (;;) {
      u32x4 f = ld_u32x4_coh(p);
      unsigned a = f.x < f.y ? f.x : f.y;
      unsigned b = f.z < f.w ? f.z : f.w;
      unsigned mn = a < b ? a : b;
      if (!__any(mn < thr)) break;
      if (++miss > 2) __builtin_amdgcn_s_sleep(1);
    }
  }
  __syncthreads();
}

// Drain own sc0sc1 data stores, then publish epoch.
__device__ __forceinline__ void bump(char* ws, unsigned ep) {
  asm volatile("s_waitcnt vmcnt(0)" ::: "memory");
  __syncthreads();
  if (threadIdx.x == 0) st_u32_coh((unsigned*)ws + blockIdx.x, ep);
}

__global__ __launch_bounds__(256, 1) void red_lstm(
    const float* __restrict__ X,   const float* __restrict__ FUT,
    const float* __restrict__ eWih0,  const float* __restrict__ eWhh0,  const float* __restrict__ eB0,
    const float* __restrict__ eWih0r, const float* __restrict__ eWhh0r, const float* __restrict__ eB0r,
    const float* __restrict__ eWih1,  const float* __restrict__ eWhh1,  const float* __restrict__ eB1,
    const float* __restrict__ eWih1r, const float* __restrict__ eWhh1r, const float* __restrict__ eB1r,
    const float* __restrict__ dWih0,  const float* __restrict__ dWhh0,  const float* __restrict__ dB0,
    const float* __restrict__ dWih1,  const float* __restrict__ dWhh1,  const float* __restrict__ dB1,
    const float* __restrict__ bW,  const float* __restrict__ bB,
    const float* __restrict__ oW,  const float* __restrict__ oB,
    float* __restrict__ OUT, char* __restrict__ ws)
{
  const int blk  = blockIdx.x;
  const int tid  = threadIdx.x;
  const int lane = tid & 63;
  const int wave = tid >> 6;
  const int n16  = lane & 15;
  const int quad = lane >> 4;
  const int rowg = wave * 16 + n16;  // batch row for A-frag loads
  const int jl   = tid & 3;          // update-thread: hidden-within-block
  const int bb   = tid >> 2;         // update-thread: batch row

  u16*   OF  = (u16*)(ws + OFF_OF);
  u16*   OBR = (u16*)(ws + OFF_OBR);
  u16*   H1F = (u16*)(ws + OFF_H1F);
  u16*   H1B = (u16*)(ws + OFF_H1B);
  u16*   DH0 = (u16*)(ws + OFF_DH0);
  u16*   DH1 = (u16*)(ws + OFF_DH1);
  float* SB  = (float*)(ws + OFF_SBUF);
  float* CD  = (float*)(ws + OFF_CDEC);

  __shared__ float g_s[64 * 20];

  // =======================================================================
  // ENCODER LAYER 0  (blocks 0..127 = fw, 128..255 = bw; 4 hidden/block)
  // Round s: wait own-group flags >= s; cached tile load of slot s.
  // =======================================================================
  {
    const bool fw = (blk < 128);
    const int  hb = fw ? blk : (blk - 128);
    const int  j0 = hb * 4;
    const int  col = j0 + (n16 & 3) + 512 * (n16 >> 2);
    const float* whh = fw ? eWhh0 : eWhh0r;
    const float* wih = fw ? eWih0 : eWih0r;
    const float* bia = fw ? eB0 : eB0r;
    u16* buf = fw ? OF : OBR;   // slot[t]=input state, slot[t+1]=output of step t

    bf16x8 B[16];
    {
      const float* wr = whh + (size_t)col * 512 + quad * 8;
      #pragma unroll
      for (int kk = 0; kk < 16; ++kk) B[kk] = loadW8(wr + kk * 32);
    }
    float wr9[4][9], b4[4];
    #pragma unroll
    for (int g = 0; g < 4; ++g) {
      int cg = j0 + jl + 512 * g;
      b4[g] = bia[cg];
      #pragma unroll
      for (int k = 0; k < 9; ++k) wr9[g][k] = wih[cg * 9 + k];
    }
    float c = 0.0f;

    #pragma unroll 1
    for (int s = 0; s < 256; ++s) {
      if (s > 0) wait_flags(ws, fw ? (unsigned)s : 0u, fw ? 0u : (unsigned)s);
      const u16* pt = buf + ((size_t)s * 64 + rowg) * 512 + quad * 8;
      bf16x8 T[16];
      #pragma unroll
      for (int kk = 0; kk < 16; ++kk) T[kk] = *(const bf16x8*)(pt + kk * 32);
      f32x4 a0 = {0.f,0.f,0.f,0.f}, a1 = {0.f,0.f,0.f,0.f};
      #pragma unroll
      for (int kk = 0; kk < 16; kk += 2) {
        a0 = MFMA16(T[kk],     B[kk],     a0);
        a1 = MFMA16(T[kk + 1], B[kk + 1], a1);
      }
      f32x4 acc = a0 + a1;
      #pragma unroll
      for (int r = 0; r < 4; ++r)
        g_s[(wave * 16 + quad * 4 + r) * 20 + n16] = acc[r];
      __syncthreads();

      const int t = fw ? s : (255 - s);
      float pre[4];
      #pragma unroll
      for (int g = 0; g < 4; ++g) pre[g] = g_s[bb * 20 + jl + 4 * g] + b4[g];
      const float* xp = X + ((size_t)bb * 256 + t) * 9;
      #pragma unroll
      for (int k = 0; k < 9; ++k) {
        float xv = xp[k];
        #pragma unroll
        for (int g = 0; g < 4; ++g) pre[g] += xv * wr9[g][k];
      }
      float h = lstm_h(pre, c);
      float hn = __shfl_down(h, 1);      // pair -> one u32 store
      if ((jl & 1) == 0) {
        unsigned pk = (unsigned)bfr(h) | ((unsigned)bfr(hn) << 16);
        st_u32_coh((unsigned*)(buf + ((size_t)(s + 1) * 64 + bb) * 512 + j0 + jl), pk);
      }
      if (s == 255) {
        int co = fw ? 0 : 512;
        st_f32_coh(SB + (size_t)bb * 2048 + co + j0 + jl, h);
        st_f32_coh(SB + (size_t)(64 + bb) * 2048 + co + j0 + jl, c);
      }
      bump(ws, (unsigned)(s + 1));
    }
  }

  // =======================================================================
  // ENCODER LAYER 1  K = 512 (own h) + 512 (of_t) + 512 (ob_t)
  // of/ob cached loads issued BEFORE the flag wait (static for s>=1).
  // =======================================================================
  {
    const bool fw = (blk < 128);
    const int  hb = fw ? blk : (blk - 128);
    const int  j0 = hb * 4;
    const int  col = j0 + (n16 & 3) + 512 * (n16 >> 2);
    const float* whh = fw ? eWhh1 : eWhh1r;
    const float* wih = fw ? eWih1 : eWih1r;
    const float* bia = fw ? eB1 : eB1r;
    u16* hsl = fw ? H1F : H1B;           // 257 write-once slots

    bf16x8 B[48];
    {
      const float* wr = whh + (size_t)col * 512 + quad * 8;
      #pragma unroll
      for (int kk = 0; kk < 16; ++kk) B[kk] = loadW8(wr + kk * 32);
      const float* wr2 = wih + (size_t)col * 1024 + quad * 8;
      #pragma unroll
      for (int kk = 0; kk < 32; ++kk) B[16 + kk] = loadW8(wr2 + kk * 32);
    }
    float b4[4];
    #pragma unroll
    for (int g = 0; g < 4; ++g) b4[g] = bia[j0 + jl + 512 * g];
    float c = 0.0f;

    #pragma unroll 1
    for (int s = 0; s < 256; ++s) {
      const int slot_of = fw ? (s + 1)   : (256 - s);
      const int slot_ob = fw ? (256 - s) : (s + 1);
      const u16* pof = OF  + ((size_t)slot_of * 64 + rowg) * 512 + quad * 8;
      const u16* pob = OBR + ((size_t)slot_ob * 64 + rowg) * 512 + quad * 8;
      // s==0 must gate BOTH groups before touching of/ob (opposite chain!).
      if (s == 0) wait_flags(ws, 256u, 256u);
      bf16x8 Tof[16], Tob[16];
      #pragma unroll
      for (int kk = 0; kk < 16; ++kk) Tof[kk] = *(const bf16x8*)(pof + kk * 32);
      #pragma unroll
      for (int kk = 0; kk < 16; ++kk) Tob[kk] = *(const bf16x8*)(pob + kk * 32);
      if (s > 0)
        wait_flags(ws, fw ? (unsigned)(256 + s) : 256u,
                       fw ? 256u : (unsigned)(256 + s));
      const u16* ph = hsl + ((size_t)s * 64 + rowg) * 512 + quad * 8;
      bf16x8 Th[16];
      #pragma unroll
      for (int kk = 0; kk < 16; ++kk) Th[kk] = *(const bf16x8*)(ph + kk * 32);

      f32x4 a0 = {0.f,0.f,0.f,0.f}, a1 = {0.f,0.f,0.f,0.f};
      #pragma unroll
      for (int kk = 0; kk < 16; kk += 2) {
        a0 = MFMA16(Tof[kk],     B[16 + kk],     a0);
        a1 = MFMA16(Tof[kk + 1], B[16 + kk + 1], a1);
      }
      #pragma unroll
      for (int kk = 0; kk < 16; kk += 2) {
        a0 = MFMA16(Tob[kk],     B[32 + kk],     a0);
        a1 = MFMA16(Tob[kk + 1], B[32 + kk + 1], a1);
      }
      #pragma unroll
      for (int kk = 0; kk < 16; kk += 2) {
        a0 = MFMA16(Th[kk],     B[kk],     a0);
        a1 = MFMA16(Th[kk + 1], B[kk + 1], a1);
      }
      f32x4 acc = a0 + a1;
      #pragma unroll
      for (int r = 0; r < 4; ++r)
        g_s[(wave * 16 + quad * 4 + r) * 20 + n16] = acc[r];
      __syncthreads();

      float pre[4];
      #pragma unroll
      for (int g = 0; g < 4; ++g) pre[g] = g_s[bb * 20 + jl + 4 * g] + b4[g];
      float h = lstm_h(pre, c);
      float hn = __shfl_down(h, 1);
      if ((jl & 1) == 0) {
        unsigned pk = (unsigned)bfr(h) | ((unsigned)bfr(hn) << 16);
        st_u32_coh((unsigned*)(hsl + ((size_t)(s + 1) * 64 + bb) * 512 + j0 + jl), pk);
      }
      if (s == 255) {
        int co = fw ? 1024 : 1536;
        st_f32_coh(SB + (size_t)bb * 2048 + co + j0 + jl, h);
        st_f32_coh(SB + (size_t)(64 + bb) * 2048 + co + j0 + jl, c);
      }
      bump(ws, (unsigned)(257 + s));
    }
  }

  // =======================================================================
  // MERGE: [h;c](128x2048) @ bidi_w^T + b, ELU (blocks 0..127; SB cached)
  // =======================================================================
  if (blk < 128) {
    wait_flags(ws, 512u, 512u);
    if (tid < 128) {
      const int cp = tid & 3;
      const int rg = tid >> 2;             // 0..31
      const int c0 = blk * 8 + cp * 2;
      const float* w0 = bW + (size_t)c0 * 2048;
      const float* w1 = w0 + 2048;
      float am0[4], am1[4];
      #pragma unroll
      for (int r = 0; r < 4; ++r) { am0[r] = bB[c0]; am1[r] = bB[c0 + 1]; }
      #pragma unroll 1
      for (int k = 0; k < 2048; k += 4) {
        float4 wa = *(const float4*)(w0 + k);
        float4 wb = *(const float4*)(w1 + k);
        #pragma unroll
        for (int r = 0; r < 4; ++r) {
          float4 a = *(const float4*)(SB + (size_t)(rg * 4 + r) * 2048 + k);
          am0[r] += a.x * wa.x + a.y * wa.y + a.z * wa.z + a.w * wa.w;
          am1[r] += a.x * wb.x + a.y * wb.y + a.z * wb.z + a.w * wb.w;
        }
      }
      const int l = c0 >> 9, j = c0 & 511;
      #pragma unroll
      for (int r = 0; r < 4; ++r) {
        int row = rg * 4 + r;
        float v0 = elu(am0[r]);
        float v1 = elu(am1[r]);
        if (row < 64) {
          u16* dst = l ? DH1 : DH0;        // slot 0
          unsigned pk = (unsigned)bfr(v0) | ((unsigned)bfr(v1) << 16);
          st_u32_coh((unsigned*)(dst + (size_t)row * 512 + j), pk);
        } else {
          st_f32_coh(CD + ((size_t)l * 64 + (row - 64)) * 512 + j, v0);
          st_f32_coh(CD + ((size_t)l * 64 + (row - 64)) * 512 + j + 1, v1);
        }
      }
    }
    bump(ws, 513u);
  } else {
    bump(ws, 513u);   // L1 group: lockstep filler (merge readiness = L0 >= 513)
  }

  // =======================================================================
  // DECODER: L0 (blk<128) with rank-1 y-feedback; L1 (blk>=128); blk128 OUT.
  // =======================================================================
  if (blk < 128) {
    const int j0 = blk * 4;
    const int col = j0 + (n16 & 3) + 512 * (n16 >> 2);
    bf16x8 BD[16], OW0[16];
    {
      const float* wr = dWhh0 + (size_t)col * 512 + quad * 8;
      #pragma unroll
      for (int kk = 0; kk < 16; ++kk) BD[kk] = loadW8(wr + kk * 32);
    }
    #pragma unroll
    for (int kk = 0; kk < 16; ++kk) {
      if (n16 == 0) OW0[kk] = loadW8(oW + quad * 8 + kk * 32);
      else { bf16x8 z = {0,0,0,0,0,0,0,0}; OW0[kk] = z; }
    }
    float wr9[4][9], b4[4];
    #pragma unroll
    for (int g = 0; g < 4; ++g) {
      int cg = j0 + jl + 512 * g;
      b4[g] = dB0[cg];
      #pragma unroll
      for (int k = 0; k < 9; ++k) wr9[g][k] = dWih0[cg * 9 + k];
    }
    const float ob0 = oB[0];
    const float xlast = X[((size_t)bb * 256 + 255) * 9];
    float c = 0.0f;

    #pragma unroll 1
    for (int t = 0; t < 96; ++t) {
      wait_flags(ws, (unsigned)(513 + t), (unsigned)(513 + t));
      if (t == 0) c = CD[(size_t)bb * 512 + j0 + jl];   // cached (gated)
      const u16* p0 = DH0 + ((size_t)t * 64 + rowg) * 512 + quad * 8;
      bf16x8 T0[16];
      #pragma unroll
      for (int kk = 0; kk < 16; ++kk) T0[kk] = *(const bf16x8*)(p0 + kk * 32);
      f32x4 a0 = {0.f,0.f,0.f,0.f}, a1 = {0.f,0.f,0.f,0.f};
      #pragma unroll
      for (int kk = 0; kk < 16; kk += 2) {
        a0 = MFMA16(T0[kk],     BD[kk],     a0);
        a1 = MFMA16(T0[kk + 1], BD[kk + 1], a1);
      }
      f32x4 acc = a0 + a1;
      #pragma unroll
      for (int r = 0; r < 4; ++r)
        g_s[(wave * 16 + quad * 4 + r) * 20 + n16] = acc[r];
      if (t >= 1) {
        const u16* p1 = DH1 + ((size_t)t * 64 + rowg) * 512 + quad * 8;
        bf16x8 T1[16];
        #pragma unroll
        for (int kk = 0; kk < 16; ++kk) T1[kk] = *(const bf16x8*)(p1 + kk * 32);
        f32x4 y0 = {0.f,0.f,0.f,0.f}, y1 = {0.f,0.f,0.f,0.f};
        #pragma unroll
        for (int kk = 0; kk < 16; kk += 2) {
          y0 = MFMA16(T1[kk],     OW0[kk],     y0);
          y1 = MFMA16(T1[kk + 1], OW0[kk + 1], y1);
        }
        f32x4 accy = y0 + y1;
        if (n16 == 0) {
          #pragma unroll
          for (int r = 0; r < 4; ++r)
            g_s[(wave * 16 + quad * 4 + r) * 20 + 16] = accy[r] + ob0;
        }
      }
      __syncthreads();

      float pre[4];
      #pragma unroll
      for (int g = 0; g < 4; ++g) pre[g] = g_s[bb * 20 + jl + 4 * g] + b4[g];
      float yp = (t == 0) ? xlast : g_s[bb * 20 + 16];
      #pragma unroll
      for (int g = 0; g < 4; ++g) pre[g] += yp * wr9[g][0];
      const float* fp = FUT + ((size_t)bb * 96 + t) * 8;
      #pragma unroll
      for (int k = 0; k < 8; ++k) {
        float fv = fp[k];
        #pragma unroll
        for (int g = 0; g < 4; ++g) pre[g] += fv * wr9[g][k + 1];
      }
      float h = lstm_h(pre, c);
      float hn = __shfl_down(h, 1);
      if ((jl & 1) == 0) {
        unsigned pk = (unsigned)bfr(h) | ((unsigned)bfr(hn) << 16);
        st_u32_coh((unsigned*)(DH0 + ((size_t)(t + 1) * 64 + bb) * 512 + j0 + jl), pk);
      }
      bump(ws, (unsigned)(514 + t));
    }
  } else {
    const int hb = blk - 128;
    const int j0 = hb * 4;
    const int col = j0 + (n16 & 3) + 512 * (n16 >> 2);
    bf16x8 BD[32];
    {
      const float* wr = dWhh1 + (size_t)col * 512 + quad * 8;
      #pragma unroll
      for (int kk = 0; kk < 16; ++kk) BD[kk] = loadW8(wr + kk * 32);
      const float* wr2 = dWih1 + (size_t)col * 512 + quad * 8;
      #pragma unroll
      for (int kk = 0; kk < 16; ++kk) BD[16 + kk] = loadW8(wr2 + kk * 32);
    }
    float b4[4];
    #pragma unroll
    for (int g = 0; g < 4; ++g) b4[g] = dB1[j0 + jl + 512 * g];
    bf16x8 OBW[16];
    float obv = 0.0f;
    if (blk == 128) {
      if (n16 < 9) {
        const float* wr = oW + (size_t)n16 * 512 + quad * 8;
        #pragma unroll
        for (int kk = 0; kk < 16; ++kk) OBW[kk] = loadW8(wr + kk * 32);
        obv = oB[n16];
      } else {
        #pragma unroll
        for (int kk = 0; kk < 16; ++kk) { bf16x8 z = {0,0,0,0,0,0,0,0}; OBW[kk] = z; }
      }
    }
    float c = 0.0f;

    #pragma unroll 1
    for (int t = 0; t < 96; ++t) {
      wait_flags(ws, (unsigned)(514 + t), (unsigned)(513 + t));
      if (t == 0) c = CD[((size_t)64 + bb) * 512 + j0 + jl];   // cached (gated)
      const u16* p1 = DH1 + ((size_t)t * 64 + rowg) * 512 + quad * 8;
      const u16* p0 = DH0 + ((size_t)(t + 1) * 64 + rowg) * 512 + quad * 8;
      bf16x8 Th1[16], T0[16];
      #pragma unroll
      for (int kk = 0; kk < 16; ++kk) Th1[kk] = *(const bf16x8*)(p1 + kk * 32);
      #pragma unroll
      for (int kk = 0; kk < 16; ++kk) T0[kk] = *(const bf16x8*)(p0 + kk * 32);
      f32x4 a0 = {0.f,0.f,0.f,0.f}, a1 = {0.f,0.f,0.f,0.f};
      #pragma unroll
      for (int kk = 0; kk < 16; kk += 2) {
        a0 = MFMA16(Th1[kk],     BD[kk],     a0);
        a1 = MFMA16(Th1[kk + 1], BD[kk + 1], a1);
      }
      #pragma unroll
      for (int kk = 0; kk < 16; kk += 2) {
        a0 = MFMA16(T0[kk],     BD[16 + kk],     a0);
        a1 = MFMA16(T0[kk + 1], BD[16 + kk + 1], a1);
      }
      f32x4 acc = a0 + a1;
      #pragma unroll
      for (int r = 0; r < 4; ++r)
        g_s[(wave * 16 + quad * 4 + r) * 20 + n16] = acc[r];
      __syncthreads();

      float pre[4];
      #pragma unroll
      for (int g = 0; g < 4; ++g) pre[g] = g_s[bb * 20 + jl + 4 * g] + b4[g];
      float h = lstm_h(pre, c);
      float hn = __shfl_down(h, 1);
      if ((jl & 1) == 0) {
        unsigned pk = (unsigned)bfr(h) | ((unsigned)bfr(hn) << 16);
        st_u32_coh((unsigned*)(DH1 + ((size_t)(t + 1) * 64 + bb) * 512 + j0 + jl), pk);
      }
      bump(ws, (unsigned)(514 + t));
      // blk128: y_{t-1} -> OUT, off the critical path (after the bump).
      if (blk == 128 && t >= 1) {
        f32x4 y0 = {0.f,0.f,0.f,0.f}, y1 = {0.f,0.f,0.f,0.f};
        #pragma unroll
        for (int kk = 0; kk < 16; kk += 2) {
          y0 = MFMA16(Th1[kk],     OBW[kk],     y0);
          y1 = MFMA16(Th1[kk + 1], OBW[kk + 1], y1);
        }
        f32x4 accy = y0 + y1;
        #pragma unroll
        for (int r = 0; r < 4; ++r) {
          int b = wave * 16 + quad * 4 + r;
          float v = accy[r] + obv;
          if (n16 < 9) OUT[(size_t)b * 864 + (size_t)(t - 1) * 9 + n16] = v;
        }
      }
    }
    if (blk == 128) {  // final output row t=95 (h1_95 = DH1 slot 96)
      wait_flags(ws, 0u, 609u);
      const u16* p1 = DH1 + ((size_t)96 * 64 + rowg) * 512 + quad * 8;
      bf16x8 T[16];
      #pragma unroll
      for (int kk = 0; kk < 16; ++kk) T[kk] = *(const bf16x8*)(p1 + kk * 32);
      f32x4 y0 = {0.f,0.f,0.f,0.f}, y1 = {0.f,0.f,0.f,0.f};
      #pragma unroll
      for (int kk = 0; kk < 16; kk += 2) {
        y0 = MFMA16(T[kk],     OBW[kk],     y0);
        y1 = MFMA16(T[kk + 1], OBW[kk + 1], y1);
      }
      f32x4 accy = y0 + y1;
      #pragma unroll
      for (int r = 0; r < 4; ++r) {
        int b = wave * 16 + quad * 4 + r;
        float v = accy[r] + obv;
        if (n16 < 9) OUT[(size_t)b * 864 + (size_t)95 * 9 + n16] = v;
      }
    }
  }
}

extern "C" void kernel_launch(void* const* d_in, const int* in_sizes, int n_in,
                              void* d_out, int out_size, void* d_ws, size_t ws_size,
                              hipStream_t stream) {
  (void)in_sizes; (void)n_in; (void)out_size;
  if (ws_size < WS_NEED) return;

  const float* X      = (const float*)d_in[0];
  const float* FUT    = (const float*)d_in[1];
  const float* eWih0  = (const float*)d_in[3];
  const float* eWhh0  = (const float*)d_in[4];
  const float* eB0    = (const float*)d_in[5];
  const float* eWih0r = (const float*)d_in[6];
  const float* eWhh0r = (const float*)d_in[7];
  const float* eB0r   = (const float*)d_in[8];
  const float* eWih1  = (const float*)d_in[9];
  const float* eWhh1  = (const float*)d_in[10];
  const float* eB1    = (const float*)d_in[11];
  const float* eWih1r = (const float*)d_in[12];
  const float* eWhh1r = (const float*)d_in[13];
  const float* eB1r   = (const float*)d_in[14];
  const float* dWih0  = (const float*)d_in[15];
  const float* dWhh0  = (const float*)d_in[16];
  const float* dB0    = (const float*)d_in[17];
  const float* dWih1  = (const float*)d_in[18];
  const float* dWhh1  = (const float*)d_in[19];
  const float* dB1    = (const float*)d_in[20];
  const float* bW     = (const float*)d_in[21];
  const float* bB     = (const float*)d_in[22];
  const float* oW     = (const float*)d_in[23];
  const float* oB     = (const float*)d_in[24];

  char* ws = (char*)d_ws;
  hipMemsetAsync(ws, 0, 4096, stream);                 // epoch flags
  hipMemsetAsync(ws + OFF_OF,  0, SZ_SLOT, stream);    // enc L0 fw h(-1) = 0
  hipMemsetAsync(ws + OFF_OBR, 0, SZ_SLOT, stream);    // enc L0 bw h(+1) = 0
  hipMemsetAsync(ws + OFF_H1F, 0, SZ_SLOT, stream);    // enc L1 fw h init
  hipMemsetAsync(ws + OFF_H1B, 0, SZ_SLOT, stream);    // enc L1 bw h init

  red_lstm<<<BLOCKS, 256, 0, stream>>>(
      X, FUT,
      eWih0, eWhh0, eB0, eWih0r, eWhh0r, eB0r,
      eWih1, eWhh1, eB1, eWih1r, eWhh1r, eB1r,
      dWih0, dWhh0, dB0, dWih1, dWhh1, dB1,
      bW, bB, oW, oB,
      (float*)d_out, ws);
}

// Round 4
// 4116.602 us; speedup vs baseline: 1.3850x; 1.3697x over previous
//
#include <hip/hip_runtime.h>

// ---------------------------------------------------------------------------
// RecurrentEncoderDecoder: persistent-kernel LSTM seq2seq on MI355X (gfx950)
// B=64, H=512, T_enc=256, T_dec=96. 256 blocks x 256 thr.
// R5: SCOPE-REDUCED dataflow. Batch dim split into 4 independent groups of
// 16; each direction-chain = 32 blocks x 16 hidden. 8 independent pipelines
// (4 groups x fw/bw), each with its own flag set (1 flag per cache line,
// single-hop direct polling over 32 flags). Tiles are [16][512] bf16 (16KB).
// Numerics/MFMA mapping identical to the R2-proven kernel, just re-scoped.
// All cross-block data: sc0sc1 stores; tile loads coherent sc0sc1 (R2 path).
// Epochs per chain: encL0 s+1 (1..256); encL1 257+s (..512); merge 513;
// dec 514+t (..609).
// ---------------------------------------------------------------------------

#define BLOCKS 256

typedef short bf16x8 __attribute__((ext_vector_type(8)));
typedef float f32x4  __attribute__((ext_vector_type(4)));
typedef unsigned short u16;

__device__ __forceinline__ f32x4 MFMA16(bf16x8 a, bf16x8 b, f32x4 c) {
  return __builtin_amdgcn_mfma_f32_16x16x32_bf16(a, b, c, 0, 0, 0);
}

__device__ __forceinline__ u16 bfr(float f) {  // fp32 -> bf16 RNE
  unsigned u = __float_as_uint(f);
  u += 0x7FFFu + ((u >> 16) & 1u);
  return (u16)(u >> 16);
}
__device__ __forceinline__ bf16x8 pack8(float4 a, float4 b) {
  bf16x8 r;
  r[0] = (short)bfr(a.x); r[1] = (short)bfr(a.y); r[2] = (short)bfr(a.z); r[3] = (short)bfr(a.w);
  r[4] = (short)bfr(b.x); r[5] = (short)bfr(b.y); r[6] = (short)bfr(b.z); r[7] = (short)bfr(b.w);
  return r;
}
__device__ __forceinline__ bf16x8 loadW8(const float* p) {
  float4 a = *(const float4*)p;
  float4 b = *(const float4*)(p + 4);
  return pack8(a, b);
}
__device__ __forceinline__ float sigm(float x) { return 1.0f / (1.0f + __expf(-x)); }
__device__ __forceinline__ float tanh_f(float x) {
  float a = fabsf(x);
  float e = __expf(-2.0f * a);
  float t = (1.0f - e) / (1.0f + e);
  return x < 0.0f ? -t : t;
}
__device__ __forceinline__ float lstm_h(const float pre[4], float& c) {
  float ig = sigm(pre[0]);
  float fg = sigm(pre[1]);
  float gg = tanh_f(pre[2]);
  float og = sigm(pre[3]);
  c = fg * c + ig * gg;
  return og * tanh_f(c);
}
__device__ __forceinline__ float elu(float v) { return v > 0.f ? v : (__expf(v) - 1.0f); }

// ---- coherent (IF$-level) helpers ----
__device__ __forceinline__ void st_u32_coh(unsigned* p, unsigned v) {
  asm volatile("global_store_dword %0, %1, off sc0 sc1" :: "v"(p), "v"(v) : "memory");
}
__device__ __forceinline__ void st_f32_coh(float* p, float v) {
  asm volatile("global_store_dword %0, %1, off sc0 sc1" :: "v"(p), "v"(v) : "memory");
}
__device__ __forceinline__ void st_b16_coh(u16* p, u16 v) {
  unsigned uv = v;
  asm volatile("global_store_short %0, %1, off sc0 sc1" :: "v"(p), "v"(uv) : "memory");
}
__device__ __forceinline__ unsigned ld_u32_coh(const unsigned* p) {
  unsigned r;
  asm volatile("global_load_dword %0, %1, off sc0 sc1\n\ts_waitcnt vmcnt(0)"
               : "=&v"(r) : "v"(p) : "memory");
  return r;
}
// Load one A-tile (16 bf16x8 frags, 64B stride) coherently; waits vmcnt(0).
__device__ __forceinline__ void ld_tile_coh(const u16* base, bf16x8 f[16]) {
  asm volatile(
    "global_load_dwordx4 %0, %16, off sc0 sc1\n\t"
    "global_load_dwordx4 %1, %16, off offset:64 sc0 sc1\n\t"
    "global_load_dwordx4 %2, %16, off offset:128 sc0 sc1\n\t"
    "global_load_dwordx4 %3, %16, off offset:192 sc0 sc1\n\t"
    "global_load_dwordx4 %4, %16, off offset:256 sc0 sc1\n\t"
    "global_load_dwordx4 %5, %16, off offset:320 sc0 sc1\n\t"
    "global_load_dwordx4 %6, %16, off offset:384 sc0 sc1\n\t"
    "global_load_dwordx4 %7, %16, off offset:448 sc0 sc1\n\t"
    "global_load_dwordx4 %8, %16, off offset:512 sc0 sc1\n\t"
    "global_load_dwordx4 %9, %16, off offset:576 sc0 sc1\n\t"
    "global_load_dwordx4 %10, %16, off offset:640 sc0 sc1\n\t"
    "global_load_dwordx4 %11, %16, off offset:704 sc0 sc1\n\t"
    "global_load_dwordx4 %12, %16, off offset:768 sc0 sc1\n\t"
    "global_load_dwordx4 %13, %16, off offset:832 sc0 sc1\n\t"
    "global_load_dwordx4 %14, %16, off offset:896 sc0 sc1\n\t"
    "global_load_dwordx4 %15, %16, off offset:960 sc0 sc1\n\t"
    "s_waitcnt vmcnt(0)"
    : "=&v"(f[0]), "=&v"(f[1]), "=&v"(f[2]), "=&v"(f[3]),
      "=&v"(f[4]), "=&v"(f[5]), "=&v"(f[6]), "=&v"(f[7]),
      "=&v"(f[8]), "=&v"(f[9]), "=&v"(f[10]), "=&v"(f[11]),
      "=&v"(f[12]), "=&v"(f[13]), "=&v"(f[14]), "=&v"(f[15])
    : "v"(base)
    : "memory");
}
// Same but WITHOUT the wait — caller does vmcnt(0) + sched_barrier(0).
__device__ __forceinline__ void ld_tile_issue(const u16* base, bf16x8 f[16]) {
  asm volatile(
    "global_load_dwordx4 %0, %16, off sc0 sc1\n\t"
    "global_load_dwordx4 %1, %16, off offset:64 sc0 sc1\n\t"
    "global_load_dwordx4 %2, %16, off offset:128 sc0 sc1\n\t"
    "global_load_dwordx4 %3, %16, off offset:192 sc0 sc1\n\t"
    "global_load_dwordx4 %4, %16, off offset:256 sc0 sc1\n\t"
    "global_load_dwordx4 %5, %16, off offset:320 sc0 sc1\n\t"
    "global_load_dwordx4 %6, %16, off offset:384 sc0 sc1\n\t"
    "global_load_dwordx4 %7, %16, off offset:448 sc0 sc1\n\t"
    "global_load_dwordx4 %8, %16, off offset:512 sc0 sc1\n\t"
    "global_load_dwordx4 %9, %16, off offset:576 sc0 sc1\n\t"
    "global_load_dwordx4 %10, %16, off offset:640 sc0 sc1\n\t"
    "global_load_dwordx4 %11, %16, off offset:704 sc0 sc1\n\t"
    "global_load_dwordx4 %12, %16, off offset:768 sc0 sc1\n\t"
    "global_load_dwordx4 %13, %16, off offset:832 sc0 sc1\n\t"
    "global_load_dwordx4 %14, %16, off offset:896 sc0 sc1\n\t"
    "global_load_dwordx4 %15, %16, off offset:960 sc0 sc1"
    : "=&v"(f[0]), "=&v"(f[1]), "=&v"(f[2]), "=&v"(f[3]),
      "=&v"(f[4]), "=&v"(f[5]), "=&v"(f[6]), "=&v"(f[7]),
      "=&v"(f[8]), "=&v"(f[9]), "=&v"(f[10]), "=&v"(f[11]),
      "=&v"(f[12]), "=&v"(f[13]), "=&v"(f[14]), "=&v"(f[15])
    : "v"(base)
    : "memory");
}

// ---- workspace layout ----
static constexpr size_t SLOTB   = (size_t)16 * 512 * 2;     // [16][512] bf16 = 16KB
static constexpr size_t SLOTE   = (size_t)16 * 512;         // elems
static constexpr size_t OFF_OF  = 65536;                    // 4 grp x 257 slots
static constexpr size_t OFF_OBR = OFF_OF  + 4 * 257 * SLOTB;
static constexpr size_t OFF_H1F = OFF_OBR + 4 * 257 * SLOTB;
static constexpr size_t OFF_H1B = OFF_H1F + 4 * 257 * SLOTB;
static constexpr size_t OFF_DH0 = OFF_H1B + 4 * 257 * SLOTB; // 4 grp x 97
static constexpr size_t OFF_DH1 = OFF_DH0 + 4 * 97 * SLOTB;
static constexpr size_t OFF_SBUF= OFF_DH1 + 4 * 97 * SLOTB;  // fp32 [128][2048]
static constexpr size_t OFF_CD  = OFF_SBUF + (size_t)128 * 2048 * 4; // 4 grp x [2][16][512] f32
static constexpr size_t WS_NEED = OFF_CD + (size_t)4 * 2 * 16 * 512 * 4;

// flags: 8 chains x 32 members, ONE FLAG PER 64B LINE (no store contention).
// chain c member m at byte (c*32+m)*64.  chains: fw grp g -> g, bw -> 4+g.
__device__ __forceinline__ void bump(char* ws, int chain, int m, unsigned ep) {
  asm volatile("s_waitcnt vmcnt(0)" ::: "memory");  // drain own data stores
  __syncthreads();
  if (threadIdx.x == 0)
    st_u32_coh((unsigned*)(ws + ((size_t)(chain * 32 + m) << 6)), ep);
}
// lanes 0-31 watch chain cA (lane = member), 32-63 chain cB; single hop.
__device__ __forceinline__ void waitc(char* ws, int cA, unsigned thrA,
                                      int cB, unsigned thrB) {
  const int t = threadIdx.x;
  if (t < 64) {
    const int c = (t < 32) ? cA : cB;
    const unsigned thr = (t < 32) ? thrA : thrB;
    const unsigned* p = (const unsigned*)(ws + ((size_t)(c * 32 + (t & 31)) << 6));
    int miss = 0;
    while (ld_u32_coh(p) < thr) {
      if (++miss > 1) __builtin_amdgcn_s_sleep(1);
    }
  }
  __syncthreads();
}

__global__ __launch_bounds__(256, 1) void red_lstm(
    const float* __restrict__ X,   const float* __restrict__ FUT,
    const float* __restrict__ eWih0,  const float* __restrict__ eWhh0,  const float* __restrict__ eB0,
    const float* __restrict__ eWih0r, const float* __restrict__ eWhh0r, const float* __restrict__ eB0r,
    const float* __restrict__ eWih1,  const float* __restrict__ eWhh1,  const float* __restrict__ eB1,
    const float* __restrict__ eWih1r, const float* __restrict__ eWhh1r, const float* __restrict__ eB1r,
    const float* __restrict__ dWih0,  const float* __restrict__ dWhh0,  const float* __restrict__ dB0,
    const float* __restrict__ dWih1,  const float* __restrict__ dWhh1,  const float* __restrict__ dB1,
    const float* __restrict__ bW,  const float* __restrict__ bB,
    const float* __restrict__ oW,  const float* __restrict__ oB,
    float* __restrict__ OUT, char* __restrict__ ws)
{
  const int blk  = blockIdx.x;
  const int tid  = threadIdx.x;
  const int lane = tid & 63;
  const int wave = tid >> 6;
  const int n16  = lane & 15;
  const int quad = lane >> 4;
  const bool fw  = (blk < 128);
  const int grp  = (blk >> 5) & 3;   // batch group 0..3
  const int m    = blk & 31;         // member in chain 0..31
  const int ownc = fw ? grp : 4 + grp;
  const int othc = fw ? 4 + grp : grp;
  const int j0   = m * 16;           // hidden base (16 per block)
  const int b0   = grp * 16;         // batch base
  const int jl   = tid & 15;         // update: hidden-within-block
  const int bb   = tid >> 4;         // update: batch row (0..15)
  // per-wave gate-column base: 4 hidden x 4 gates = 16 cols
  const int colw = j0 + wave * 4 + (n16 & 3) + 512 * (n16 >> 2);

  u16* OFg  = (u16*)(ws + OFF_OF)  + (size_t)grp * 257 * SLOTE;
  u16* OBRg = (u16*)(ws + OFF_OBR) + (size_t)grp * 257 * SLOTE;
  u16* H1Fg = (u16*)(ws + OFF_H1F) + (size_t)grp * 257 * SLOTE;
  u16* H1Bg = (u16*)(ws + OFF_H1B) + (size_t)grp * 257 * SLOTE;
  u16* DH0g = (u16*)(ws + OFF_DH0) + (size_t)grp * 97 * SLOTE;
  u16* DH1g = (u16*)(ws + OFF_DH1) + (size_t)grp * 97 * SLOTE;
  float* SB  = (float*)(ws + OFF_SBUF);
  float* CDg = (float*)(ws + OFF_CD) + (size_t)grp * 2 * 16 * 512;

  __shared__ float g_s[16 * 68];   // [16 batches][64 gate cols + y + pad]

  // =======================================================================
  // ENCODER LAYER 0  (8 independent 32-block chains)
  // =======================================================================
  {
    const float* whh = fw ? eWhh0 : eWhh0r;
    const float* wih = fw ? eWih0 : eWih0r;
    const float* bia = fw ? eB0 : eB0r;
    u16* buf = fw ? OFg : OBRg;   // slot[t]=input state, slot[t+1]=output

    bf16x8 B[16];
    {
      const float* wr = whh + (size_t)colw * 512 + quad * 8;
      #pragma unroll
      for (int kk = 0; kk < 16; ++kk) B[kk] = loadW8(wr + kk * 32);
    }
    float wr9[4][9], b4[4];
    #pragma unroll
    for (int g = 0; g < 4; ++g) {
      int cg = j0 + jl + 512 * g;
      b4[g] = bia[cg];
      #pragma unroll
      for (int k = 0; k < 9; ++k) wr9[g][k] = wih[cg * 9 + k];
    }
    float c = 0.0f;

    #pragma unroll 1
    for (int s = 0; s < 256; ++s) {
      if (s > 0) waitc(ws, ownc, (unsigned)s, ownc, (unsigned)s);
      bf16x8 T[16];
      ld_tile_coh(buf + ((size_t)s * 16 + n16) * 512 + quad * 8, T);
      f32x4 a0 = {0.f,0.f,0.f,0.f}, a1 = {0.f,0.f,0.f,0.f};
      #pragma unroll
      for (int kk = 0; kk < 16; kk += 2) {
        a0 = MFMA16(T[kk],     B[kk],     a0);
        a1 = MFMA16(T[kk + 1], B[kk + 1], a1);
      }
      f32x4 acc = a0 + a1;
      #pragma unroll
      for (int r = 0; r < 4; ++r)
        g_s[(quad * 4 + r) * 68 + ((wave * 4 + (n16 & 3)) << 2) + (n16 >> 2)] = acc[r];
      __syncthreads();

      const int t = fw ? s : (255 - s);
      float pre[4];
      #pragma unroll
      for (int g = 0; g < 4; ++g) pre[g] = g_s[bb * 68 + jl * 4 + g] + b4[g];
      const float* xp = X + ((size_t)(b0 + bb) * 256 + t) * 9;
      #pragma unroll
      for (int k = 0; k < 9; ++k) {
        float xv = xp[k];
        #pragma unroll
        for (int g = 0; g < 4; ++g) pre[g] += xv * wr9[g][k];
      }
      float h = lstm_h(pre, c);
      float hn = __shfl_down(h, 1);
      if ((jl & 1) == 0) {
        unsigned pk = (unsigned)bfr(h) | ((unsigned)bfr(hn) << 16);
        st_u32_coh((unsigned*)(buf + ((size_t)(s + 1) * 16 + bb) * 512 + j0 + jl), pk);
      }
      if (s == 255) {
        int co = fw ? 0 : 512;
        st_f32_coh(SB + (size_t)(b0 + bb) * 2048 + co + j0 + jl, h);
        st_f32_coh(SB + (size_t)(64 + b0 + bb) * 2048 + co + j0 + jl, c);
      }
      bump(ws, ownc, m, (unsigned)(s + 1));
    }
  }

  // =======================================================================
  // ENCODER LAYER 1  K = 512(own h, gated) + 512(of) + 512(ob) (static)
  // =======================================================================
  {
    const float* whh = fw ? eWhh1 : eWhh1r;
    const float* wih = fw ? eWih1 : eWih1r;
    const float* bia = fw ? eB1 : eB1r;
    u16* hsl = fw ? H1Fg : H1Bg;

    bf16x8 B[48];
    {
      const float* wr = whh + (size_t)colw * 512 + quad * 8;
      #pragma unroll
      for (int kk = 0; kk < 16; ++kk) B[kk] = loadW8(wr + kk * 32);
      const float* wr2 = wih + (size_t)colw * 1024 + quad * 8;
      #pragma unroll
      for (int kk = 0; kk < 32; ++kk) B[16 + kk] = loadW8(wr2 + kk * 32);
    }
    float b4[4];
    #pragma unroll
    for (int g = 0; g < 4; ++g) b4[g] = bia[j0 + jl + 512 * g];
    float c = 0.0f;

    #pragma unroll 1
    for (int s = 0; s < 256; ++s) {
      const int slot_of = fw ? (s + 1)   : (256 - s);
      const int slot_ob = fw ? (256 - s) : (s + 1);
      if (s == 0) waitc(ws, othc, 256u, othc, 256u);  // other L0 chain done
      f32x4 a0 = {0.f,0.f,0.f,0.f}, a1 = {0.f,0.f,0.f,0.f};
      {
        bf16x8 Tof[16], Tob[16];
        ld_tile_issue(OFg  + ((size_t)slot_of * 16 + n16) * 512 + quad * 8, Tof);
        ld_tile_issue(OBRg + ((size_t)slot_ob * 16 + n16) * 512 + quad * 8, Tob);
        asm volatile("s_waitcnt vmcnt(0)" ::: "memory");
        __builtin_amdgcn_sched_barrier(0);
        #pragma unroll
        for (int kk = 0; kk < 16; kk += 2) {
          a0 = MFMA16(Tof[kk],     B[16 + kk],     a0);
          a1 = MFMA16(Tof[kk + 1], B[16 + kk + 1], a1);
        }
        #pragma unroll
        for (int kk = 0; kk < 16; kk += 2) {
          a0 = MFMA16(Tob[kk],     B[32 + kk],     a0);
          a1 = MFMA16(Tob[kk + 1], B[32 + kk + 1], a1);
        }
      }
      if (s > 0) waitc(ws, ownc, (unsigned)(256 + s), ownc, (unsigned)(256 + s));
      {
        bf16x8 Th[16];
        ld_tile_coh(hsl + ((size_t)s * 16 + n16) * 512 + quad * 8, Th);
        #pragma unroll
        for (int kk = 0; kk < 16; kk += 2) {
          a0 = MFMA16(Th[kk],     B[kk],     a0);
          a1 = MFMA16(Th[kk + 1], B[kk + 1], a1);
        }
      }
      f32x4 acc = a0 + a1;
      #pragma unroll
      for (int r = 0; r < 4; ++r)
        g_s[(quad * 4 + r) * 68 + ((wave * 4 + (n16 & 3)) << 2) + (n16 >> 2)] = acc[r];
      __syncthreads();

      float pre[4];
      #pragma unroll
      for (int g = 0; g < 4; ++g) pre[g] = g_s[bb * 68 + jl * 4 + g] + b4[g];
      float h = lstm_h(pre, c);
      float hn = __shfl_down(h, 1);
      if ((jl & 1) == 0) {
        unsigned pk = (unsigned)bfr(h) | ((unsigned)bfr(hn) << 16);
        st_u32_coh((unsigned*)(hsl + ((size_t)(s + 1) * 16 + bb) * 512 + j0 + jl), pk);
      }
      if (s == 255) {
        int co = fw ? 1024 : 1536;
        st_f32_coh(SB + (size_t)(b0 + bb) * 2048 + co + j0 + jl, h);
        st_f32_coh(SB + (size_t)(64 + b0 + bb) * 2048 + co + j0 + jl, c);
      }
      bump(ws, ownc, m, (unsigned)(257 + s));
    }
  }

  // =======================================================================
  // MERGE (per group): [h;c](16x2048 rows of SB) @ bidi_w^T + b, ELU.
  // fw block m -> cols m*16..+15 of l=0; bw block -> same of l=1.
  // =======================================================================
  {
    waitc(ws, grp, 512u, 4 + grp, 512u);
    const int rr = tid >> 4;          // batch-local row
    const int cc = tid & 15;          // col within block's 16
    const int l  = fw ? 0 : 1;
    const int colm = l * 512 + m * 16 + cc;
    const float* wrow = bW + (size_t)colm * 2048;
    const float* ah = SB + (size_t)(b0 + rr) * 2048;
    const float* ac = SB + (size_t)(64 + b0 + rr) * 2048;
    float amh = bB[colm], amc = bB[colm];
    #pragma unroll 1
    for (int k = 0; k < 2048; k += 4) {
      float4 w = *(const float4*)(wrow + k);
      float4 vh = *(const float4*)(ah + k);
      float4 vc = *(const float4*)(ac + k);
      amh += vh.x * w.x + vh.y * w.y + vh.z * w.z + vh.w * w.w;
      amc += vc.x * w.x + vc.y * w.y + vc.z * w.z + vc.w * w.w;
    }
    float vh = elu(amh), vc = elu(amc);
    u16* dst = l ? DH1g : DH0g;       // slot 0
    st_b16_coh(dst + (size_t)rr * 512 + m * 16 + cc, bfr(vh));
    st_f32_coh(CDg + ((size_t)l * 16 + rr) * 512 + m * 16 + cc, vc);
    bump(ws, ownc, m, 513u);
  }

  // =======================================================================
  // DECODER (per group): fw chain = L0 (+rank-1 y via out_w row 0);
  // bw chain = L1; bw m==0 wave0 writes OUT (off critical path).
  // =======================================================================
  if (fw) {
    bf16x8 BD[16], OW0[16];
    {
      const float* wr = dWhh0 + (size_t)colw * 512 + quad * 8;
      #pragma unroll
      for (int kk = 0; kk < 16; ++kk) BD[kk] = loadW8(wr + kk * 32);
    }
    #pragma unroll
    for (int kk = 0; kk < 16; ++kk) {
      if (wave == 0 && n16 == 0) OW0[kk] = loadW8(oW + quad * 8 + kk * 32);
      else { bf16x8 z = {0,0,0,0,0,0,0,0}; OW0[kk] = z; }
    }
    float wr9[4][9], b4[4];
    #pragma unroll
    for (int g = 0; g < 4; ++g) {
      int cg = j0 + jl + 512 * g;
      b4[g] = dB0[cg];
      #pragma unroll
      for (int k = 0; k < 9; ++k) wr9[g][k] = dWih0[cg * 9 + k];
    }
    const float ob0 = oB[0];
    const float xlast = X[((size_t)(b0 + bb) * 256 + 255) * 9];
    float c = 0.0f;

    #pragma unroll 1
    for (int t = 0; t < 96; ++t) {
      waitc(ws, ownc, (unsigned)(513 + t), othc, (unsigned)(513 + t));
      if (t == 0) c = CDg[(size_t)bb * 512 + j0 + jl];   // merge-gated, fresh
      bf16x8 T0[16], T1[16];
      ld_tile_issue(DH0g + ((size_t)t * 16 + n16) * 512 + quad * 8, T0);
      if (t >= 1 && wave == 0)
        ld_tile_issue(DH1g + ((size_t)t * 16 + n16) * 512 + quad * 8, T1);
      asm volatile("s_waitcnt vmcnt(0)" ::: "memory");
      __builtin_amdgcn_sched_barrier(0);
      f32x4 a0 = {0.f,0.f,0.f,0.f}, a1 = {0.f,0.f,0.f,0.f};
      #pragma unroll
      for (int kk = 0; kk < 16; kk += 2) {
        a0 = MFMA16(T0[kk],     BD[kk],     a0);
        a1 = MFMA16(T0[kk + 1], BD[kk + 1], a1);
      }
      f32x4 acc = a0 + a1;
      #pragma unroll
      for (int r = 0; r < 4; ++r)
        g_s[(quad * 4 + r) * 68 + ((wave * 4 + (n16 & 3)) << 2) + (n16 >> 2)] = acc[r];
      if (t >= 1 && wave == 0) {
        f32x4 y0 = {0.f,0.f,0.f,0.f}, y1 = {0.f,0.f,0.f,0.f};
        #pragma unroll
        for (int kk = 0; kk < 16; kk += 2) {
          y0 = MFMA16(T1[kk],     OW0[kk],     y0);
          y1 = MFMA16(T1[kk + 1], OW0[kk + 1], y1);
        }
        f32x4 accy = y0 + y1;
        if (n16 == 0) {
          #pragma unroll
          for (int r = 0; r < 4; ++r)
            g_s[(quad * 4 + r) * 68 + 64] = accy[r] + ob0;
        }
      }
      __syncthreads();

      float pre[4];
      #pragma unroll
      for (int g = 0; g < 4; ++g) pre[g] = g_s[bb * 68 + jl * 4 + g] + b4[g];
      float yp = (t == 0) ? xlast : g_s[bb * 68 + 64];
      #pragma unroll
      for (int g = 0; g < 4; ++g) pre[g] += yp * wr9[g][0];
      const float* fp = FUT + ((size_t)(b0 + bb) * 96 + t) * 8;
      #pragma unroll
      for (int k = 0; k < 8; ++k) {
        float fv = fp[k];
        #pragma unroll
        for (int g = 0; g < 4; ++g) pre[g] += fv * wr9[g][k + 1];
      }
      float h = lstm_h(pre, c);
      float hn = __shfl_down(h, 1);
      if ((jl & 1) == 0) {
        unsigned pk = (unsigned)bfr(h) | ((unsigned)bfr(hn) << 16);
        st_u32_coh((unsigned*)(DH0g + ((size_t)(t + 1) * 16 + bb) * 512 + j0 + jl), pk);
      }
      bump(ws, ownc, m, (unsigned)(514 + t));
    }
  } else {
    const bool outblk = (m == 0);
    bf16x8 BD[32];
    {
      const float* wr = dWhh1 + (size_t)colw * 512 + quad * 8;
      #pragma unroll
      for (int kk = 0; kk < 16; ++kk) BD[kk] = loadW8(wr + kk * 32);
      const float* wr2 = dWih1 + (size_t)colw * 512 + quad * 8;
      #pragma unroll
      for (int kk = 0; kk < 16; ++kk) BD[16 + kk] = loadW8(wr2 + kk * 32);
    }
    float b4[4];
    #pragma unroll
    for (int g = 0; g < 4; ++g) b4[g] = dB1[j0 + jl + 512 * g];
    bf16x8 OBW[16];
    float obv = 0.0f;
    if (outblk && wave == 0 && n16 < 9) {
      const float* wr = oW + (size_t)n16 * 512 + quad * 8;
      #pragma unroll
      for (int kk = 0; kk < 16; ++kk) OBW[kk] = loadW8(wr + kk * 32);
      obv = oB[n16];
    } else {
      #pragma unroll
      for (int kk = 0; kk < 16; ++kk) { bf16x8 z = {0,0,0,0,0,0,0,0}; OBW[kk] = z; }
    }
    float c = 0.0f;

    #pragma unroll 1
    for (int t = 0; t < 96; ++t) {
      waitc(ws, ownc, (unsigned)(513 + t), othc, (unsigned)(514 + t));
      if (t == 0) c = CDg[((size_t)16 + bb) * 512 + j0 + jl];
      bf16x8 Th1[16], T0[16];
      ld_tile_issue(DH1g + ((size_t)t * 16 + n16) * 512 + quad * 8, Th1);
      ld_tile_issue(DH0g + ((size_t)(t + 1) * 16 + n16) * 512 + quad * 8, T0);
      asm volatile("s_waitcnt vmcnt(0)" ::: "memory");
      __builtin_amdgcn_sched_barrier(0);
      f32x4 a0 = {0.f,0.f,0.f,0.f}, a1 = {0.f,0.f,0.f,0.f};
      #pragma unroll
      for (int kk = 0; kk < 16; kk += 2) {
        a0 = MFMA16(Th1[kk],     BD[kk],     a0);
        a1 = MFMA16(Th1[kk + 1], BD[kk + 1], a1);
      }
      #pragma unroll
      for (int kk = 0; kk < 16; kk += 2) {
        a0 = MFMA16(T0[kk],     BD[16 + kk],     a0);
        a1 = MFMA16(T0[kk + 1], BD[16 + kk + 1], a1);
      }
      f32x4 acc = a0 + a1;
      #pragma unroll
      for (int r = 0; r < 4; ++r)
        g_s[(quad * 4 + r) * 68 + ((wave * 4 + (n16 & 3)) << 2) + (n16 >> 2)] = acc[r];
      __syncthreads();

      float pre[4];
      #pragma unroll
      for (int g = 0; g < 4; ++g) pre[g] = g_s[bb * 68 + jl * 4 + g] + b4[g];
      float h = lstm_h(pre, c);
      float hn = __shfl_down(h, 1);
      if ((jl & 1) == 0) {
        unsigned pk = (unsigned)bfr(h) | ((unsigned)bfr(hn) << 16);
        st_u32_coh((unsigned*)(DH1g + ((size_t)(t + 1) * 16 + bb) * 512 + j0 + jl), pk);
      }
      bump(ws, ownc, m, (unsigned)(514 + t));
      // OUT y_{t-1} from Th1 (= DH1[t]) AFTER the bump, off critical path.
      if (outblk && wave == 0 && t >= 1) {
        f32x4 y0 = {0.f,0.f,0.f,0.f}, y1 = {0.f,0.f,0.f,0.f};
        #pragma unroll
        for (int kk = 0; kk < 16; kk += 2) {
          y0 = MFMA16(Th1[kk],     OBW[kk],     y0);
          y1 = MFMA16(Th1[kk + 1], OBW[kk + 1], y1);
        }
        f32x4 accy = y0 + y1;
        #pragma unroll
        for (int r = 0; r < 4; ++r) {
          float v = accy[r] + obv;
          if (n16 < 9)
            OUT[(size_t)(b0 + quad * 4 + r) * 864 + (size_t)(t - 1) * 9 + n16] = v;
        }
      }
    }
    if (outblk) {  // final row t=95: DH1 slot 96 needs whole own chain done
      waitc(ws, ownc, 609u, ownc, 609u);
      if (wave == 0) {
        bf16x8 T[16];
        ld_tile_coh(DH1g + ((size_t)96 * 16 + n16) * 512 + quad * 8, T);
        f32x4 y0 = {0.f,0.f,0.f,0.f}, y1 = {0.f,0.f,0.f,0.f};
        #pragma unroll
        for (int kk = 0; kk < 16; kk += 2) {
          y0 = MFMA16(T[kk],     OBW[kk],     y0);
          y1 = MFMA16(T[kk + 1], OBW[kk + 1], y1);
        }
        f32x4 accy = y0 + y1;
        #pragma unroll
        for (int r = 0; r < 4; ++r) {
          float v = accy[r] + obv;
          if (n16 < 9)
            OUT[(size_t)(b0 + quad * 4 + r) * 864 + (size_t)95 * 9 + n16] = v;
        }
      }
    }
  }
}

extern "C" void kernel_launch(void* const* d_in, const int* in_sizes, int n_in,
                              void* d_out, int out_size, void* d_ws, size_t ws_size,
                              hipStream_t stream) {
  (void)in_sizes; (void)n_in; (void)out_size;
  if (ws_size < WS_NEED) return;

  const float* X      = (const float*)d_in[0];
  const float* FUT    = (const float*)d_in[1];
  const float* eWih0  = (const float*)d_in[3];
  const float* eWhh0  = (const float*)d_in[4];
  const float* eB0    = (const float*)d_in[5];
  const float* eWih0r = (const float*)d_in[6];
  const float* eWhh0r = (const float*)d_in[7];
  const float* eB0r   = (const float*)d_in[8];
  const float* eWih1  = (const float*)d_in[9];
  const float* eWhh1  = (const float*)d_in[10];
  const float* eB1    = (const float*)d_in[11];
  const float* eWih1r = (const float*)d_in[12];
  const float* eWhh1r = (const float*)d_in[13];
  const float* eB1r   = (const float*)d_in[14];
  const float* dWih0  = (const float*)d_in[15];
  const float* dWhh0  = (const float*)d_in[16];
  const float* dB0    = (const float*)d_in[17];
  const float* dWih1  = (const float*)d_in[18];
  const float* dWhh1  = (const float*)d_in[19];
  const float* dB1    = (const float*)d_in[20];
  const float* bW     = (const float*)d_in[21];
  const float* bB     = (const float*)d_in[22];
  const float* oW     = (const float*)d_in[23];
  const float* oB     = (const float*)d_in[24];

  char* ws = (char*)d_ws;
  hipMemsetAsync(ws, 0, 16384, stream);                // flag lines
  for (int g = 0; g < 4; ++g) {                        // slot-0 initial states
    hipMemsetAsync(ws + OFF_OF  + (size_t)g * 257 * SLOTB, 0, SLOTB, stream);
    hipMemsetAsync(ws + OFF_OBR + (size_t)g * 257 * SLOTB, 0, SLOTB, stream);
    hipMemsetAsync(ws + OFF_H1F + (size_t)g * 257 * SLOTB, 0, SLOTB, stream);
    hipMemsetAsync(ws + OFF_H1B + (size_t)g * 257 * SLOTB, 0, SLOTB, stream);
  }

  red_lstm<<<BLOCKS, 256, 0, stream>>>(
      X, FUT,
      eWih0, eWhh0, eB0, eWih0r, eWhh0r, eB0r,
      eWih1, eWhh1, eB1, eWih1r, eWhh1r, eB1r,
      dWih0, dWhh0, dB0, dWih1, dWhh1, dB1,
      bW, bB, oW, oB,
      (float*)d_out, ws);
}